// Round 13
// baseline (1668.262 us; speedup 1.0000x reference)
//
#include <hip/hip_runtime.h>
#include <cstdint>

#define BB   4096
#define TT   7
#define INF  512
#define HH   1024
#define OUTF 512
#define G3   3072   // 3*H

typedef short bf16x8 __attribute__((ext_vector_type(8)));
typedef float f32x4  __attribute__((ext_vector_type(4)));

static __device__ __forceinline__ unsigned short f2bf(float f) {
  unsigned u = __float_as_uint(f);
  unsigned r = ((u >> 16) & 1u) + 0x7FFFu;   // RNE
  return (unsigned short)((u + r) >> 16);
}
static __device__ __forceinline__ float bf2f(unsigned short s) {
  return __uint_as_float(((unsigned)s) << 16);
}

#define GLDS16(gp, lp)                                                        \
  __builtin_amdgcn_global_load_lds(                                           \
      (const __attribute__((address_space(1))) void*)(gp),                    \
      (__attribute__((address_space(3))) void*)(lp), 16, 0, 0)

__device__ __forceinline__ int xcd_swz(int bid, int nwg) {
  return (bid & 7) * (nwg >> 3) + (bid >> 3);   // bijective: nwg % 8 == 0
}

__global__ __launch_bounds__(256)
void cvt_f32_to_bf16_x4(const float* __restrict__ in, unsigned short* __restrict__ out, int n4) {
  int i = blockIdx.x * 256 + threadIdx.x;
  if (i >= n4) return;
  const float4 v = ((const float4*)in)[i];
  ushort4 o;
  o.x = f2bf(v.x); o.y = f2bf(v.y); o.z = f2bf(v.z); o.w = f2bf(v.w);
  ((ushort4*)out)[i] = o;
}

// x [B][T][INF] f32  ->  xbT [T][B][INF] bf16 (both sides coalesced in INF)
__global__ __launch_bounds__(256)
void cvt_x_transpose(const float* __restrict__ in, unsigned short* __restrict__ out) {
  const int i4 = blockIdx.x * 256 + threadIdx.x;   // over B*T*INF/4
  const long e = (long)i4 << 2;
  const int i  = (int)(e & (INF - 1));
  const long bt = e >> 9;                          // b*T + t
  const int t = (int)(bt % TT), b = (int)(bt / TT);
  const float4 v = *(const float4*)(in + e);
  ushort4 o;
  o.x = f2bf(v.x); o.y = f2bf(v.y); o.z = f2bf(v.z); o.w = f2bf(v.w);
  *(ushort4*)(out + ((size_t)t * BB + b) * INF + i) = o;
}

// ---------------------------------------------------------------------------
// r6-verified GEMM core (best measured config): C = A @ W^T + bias.
// bf16 in, f32 acc. BK=64, double-buffered, chunk-XOR swizzle (0 conflicts).
// STAGE(next) before compute; plain __syncthreads schedule.
// mode: 0 f32; 1 f32 tanh; 2 f32 tanh+add; 3 bf16.
// NOTE: exactly ONE gemm_core call per kernel (single __shared__ instance).
// ---------------------------------------------------------------------------
template<int BM, int BN, int WM, int WN, int GN>
__device__ __forceinline__ void gemm_core(
    const unsigned short* __restrict__ A, long lda, long bm,
    const unsigned short* __restrict__ Wp, long ldw, int K,
    const float* __restrict__ biasp,
    void* __restrict__ Cp, long ldc,
    const float* __restrict__ addp, long ldadd, int mode)
{
  constexpr int ABUF = BM * 64;
  constexpr int WBUF = BN * 64;
  constexpr int AR = (BM * 8) / 256;
  constexpr int WR = (BN * 8) / 256;
  __shared__ __attribute__((aligned(16))) unsigned short sm[2 * (ABUF + WBUF)];
  unsigned short* As = sm;
  unsigned short* Ws = sm + 2 * ABUF;
  __attribute__((address_space(3))) unsigned short* lAs =
      (__attribute__((address_space(3))) unsigned short*)As;
  __attribute__((address_space(3))) unsigned short* lWs =
      (__attribute__((address_space(3))) unsigned short*)Ws;

  const int tid  = threadIdx.x;
  const int lane = tid & 63;
  const int wid  = tid >> 6;
  const int wr = (wid / GN) * (WM * 16);
  const int wc = (wid % GN) * (WN * 16);
  const int fr = lane & 15;
  const int q2 = lane >> 4;

  const unsigned short* gpa[AR];
  const unsigned short* gpw[WR];
  int lofa[AR], lofw[WR];
#pragma unroll
  for (int r = 0; r < AR; ++r) {
    const int id = r * 256 + tid;
    const int row = id >> 3, cc = id & 7;
    gpa[r] = A + (bm + row) * lda + (cc ^ (row & 7)) * 8;
    lofa[r] = id * 8;
  }
#pragma unroll
  for (int r = 0; r < WR; ++r) {
    const int id = r * 256 + tid;
    const int row = id >> 3, cc = id & 7;
    gpw[r] = Wp + (long)row * ldw + (cc ^ (row & 7)) * 8;
    lofw[r] = id * 8;
  }

#define STAGE(buf, kt) do {                                                   \
    _Pragma("unroll")                                                         \
    for (int r = 0; r < AR; ++r) GLDS16(gpa[r] + (kt), lAs + (buf) * ABUF + lofa[r]); \
    _Pragma("unroll")                                                         \
    for (int r = 0; r < WR; ++r) GLDS16(gpw[r] + (kt), lWs + (buf) * WBUF + lofw[r]); \
  } while (0)

  f32x4 acc[WM][WN] = {};
  STAGE(0, 0);
  __syncthreads();
  const int NK = K >> 6;
  for (int it = 0; it < NK; ++it) {
    const int cur = it & 1;
    if (it + 1 < NK) STAGE(cur ^ 1, (it + 1) << 6);
#pragma unroll
    for (int ks = 0; ks < 2; ++ks) {
      bf16x8 af[WM], wf[WN];
#pragma unroll
      for (int i = 0; i < WM; ++i) {
        const int row = wr + i * 16 + fr;
        const int ch  = (ks * 4 + q2) ^ (row & 7);
        af[i] = *(const bf16x8*)&As[cur * ABUF + row * 64 + ch * 8];
      }
#pragma unroll
      for (int i = 0; i < WN; ++i) {
        const int row = wc + i * 16 + fr;
        const int ch  = (ks * 4 + q2) ^ (row & 7);
        wf[i] = *(const bf16x8*)&Ws[cur * WBUF + row * 64 + ch * 8];
      }
#pragma unroll
      for (int mi = 0; mi < WM; ++mi)
#pragma unroll
        for (int ni = 0; ni < WN; ++ni)
          acc[mi][ni] = __builtin_amdgcn_mfma_f32_16x16x32_bf16(af[mi], wf[ni], acc[mi][ni], 0, 0, 0);
    }
    __syncthreads();
  }
#undef STAGE

  const int q = lane >> 4;
#pragma unroll
  for (int ni = 0; ni < WN; ++ni) {
    const int col = wc + ni * 16 + fr;
    const float bv = biasp[col];
#pragma unroll
    for (int mi = 0; mi < WM; ++mi) {
      const long row = bm + wr + mi * 16 + q * 4;
#pragma unroll
      for (int j = 0; j < 4; ++j) {
        const float v = acc[mi][ni][j] + bv;
        if (mode == 0)      ((float*)Cp)[(row + j) * ldc + col] = v;
        else if (mode == 1) ((float*)Cp)[(row + j) * ldc + col] = tanhf(v);
        else if (mode == 2) ((float*)Cp)[(row + j) * ldc + col] = tanhf(v) + addp[(row + j) * ldadd + col];
        else                ((unsigned short*)Cp)[(row + j) * ldc + col] = f2bf(v);
      }
    }
  }
}

// gi1 (bf16 out, bias incl.). by-fast mapping: each XCD's contiguous swizzle
// chunk covers few bx row-slabs x all by -> x localized per XCD (fixes the
// 8x x-overfetch measured in r12: FETCH 250 MB vs 31 MB ideal).
// Works for any grid = nbx*24. A = xbT (lda = INF).
__global__ __launch_bounds__(256)
void k_gi1(const unsigned short* __restrict__ A,
           const unsigned short* __restrict__ W, const float* __restrict__ bias,
           unsigned short* __restrict__ C)
{
  const int wg = xcd_swz(blockIdx.x, gridDim.x);
  const int by = wg % 24, bx = wg / 24;
  gemm_core<128,128,4,4,2>(A, INF, (long)bx * 128, W + (long)by * 128 * INF,
                           INF, INF, bias + by * 128, C + by * 128, G3, nullptr, 0, 3);
}

// gh1 = h1 @ Whh1^T and gh2 = h2 @ Whh2^T in one 1536-block dispatch (bf16 out)
__global__ __launch_bounds__(256)
void k_gh_dual(const unsigned short* __restrict__ h1b, const unsigned short* __restrict__ h2b,
               const unsigned short* __restrict__ W1, const unsigned short* __restrict__ W2,
               const float* __restrict__ b1, const float* __restrict__ b2,
               unsigned short* __restrict__ gh1, unsigned short* __restrict__ gh2)
{
  const int wg = xcd_swz(blockIdx.x, gridDim.x);   // 1536
  const int bx = wg % 32;
  const int by = (wg / 32) % 24;
  const int z  = wg / (32 * 24);
  const unsigned short* Aa = z ? h2b : h1b;
  const unsigned short* Ww = (z ? W2 : W1) + (long)by * 128 * HH;
  const float* bias = (z ? b2 : b1) + by * 128;
  unsigned short* C = (z ? gh2 : gh1) + by * 128;
  gemm_core<128,128,4,4,2>(Aa, HH, (long)bx * 128, Ww, HH, HH, bias, C, G3, nullptr, 0, 3);
}

// D2 merged: gi2 = h1 @ Wih2^T (bf16, by 0-23) | o1t = tanh(h1@Wo1^T+bo1)
// (f32, by 24-27) | o2(t-1): out = tanh(h2@Wo2^T+bo2) + o1t_prev (by 28-31,
// only when grid == 1024). All segments K = 1024, one gemm_core call site.
// Race-safe: o1 writes o1t_cur; o2 reads o1t_prev (ping-pong buffers);
// h2b is stable during this dispatch (gate2 launches after).
__global__ __launch_bounds__(256)
void k_gi2_o1(const unsigned short* __restrict__ h1b,
              const unsigned short* __restrict__ Wih2, const float* __restrict__ bih2,
              unsigned short* __restrict__ gi2,
              const unsigned short* __restrict__ Wo1, const float* __restrict__ bo1,
              float* __restrict__ o1t_cur,
              const unsigned short* __restrict__ h2b,
              const unsigned short* __restrict__ Wo2, const float* __restrict__ bo2,
              const float* __restrict__ o1t_prev, float* __restrict__ out_prev)
{
  const int wg = xcd_swz(blockIdx.x, gridDim.x);   // 896 or 1024
  const int bx = wg % 32;
  const int by = wg / 32;                          // 0..27 or 0..31
  const unsigned short* A = h1b;
  const unsigned short* Ww; const float* bias; void* C; long ldc; int mode;
  const float* addp = nullptr; long ldadd = 0;
  if (by < 24) {
    Ww = Wih2 + (long)by * 128 * HH; bias = bih2 + by * 128;
    C = gi2 + by * 128; ldc = G3; mode = 3;
  } else if (by < 28) {
    const int bo = by - 24;
    Ww = Wo1 + (long)bo * 128 * HH; bias = bo1 + bo * 128;
    C = o1t_cur + bo * 128; ldc = OUTF; mode = 1;
  } else {
    const int bo = by - 28;
    A = h2b;
    Ww = Wo2 + (long)bo * 128 * HH; bias = bo2 + bo * 128;
    C = out_prev + bo * 128; ldc = (long)TT * OUTF; mode = 2;
    addp = o1t_prev + bo * 128; ldadd = OUTF;
  }
  gemm_core<128,128,4,4,2>(A, HH, (long)bx * 128, Ww, HH, HH, bias, C, ldc,
                           addp, ldadd, mode);
}

// final step's output head (128 blocks, mode 2)
__global__ __launch_bounds__(256)
void k_o2f(const unsigned short* __restrict__ h2b,
           const unsigned short* __restrict__ Wo2, const float* __restrict__ bo2,
           const float* __restrict__ o1t, float* __restrict__ outp)
{
  const int wg = xcd_swz(blockIdx.x, gridDim.x);   // 128
  const int bx = wg & 31;
  const int by = wg >> 5;
  gemm_core<128,128,4,4,2>(h2b, HH, (long)bx * 128, Wo2 + (long)by * 128 * HH, HH, HH,
                           bo2 + by * 128, outp + by * 128, (long)TT * OUTF,
                           o1t + by * 128, OUTF, 2);
}

// GRU gate: h = (1-z)*n + z*h_old. gi, gh bf16; recurrence on bf16 hb (in-place).
__global__ __launch_bounds__(256)
void k_gate(const unsigned short* __restrict__ gi, long gistride,
            const unsigned short* __restrict__ gh,
            unsigned short* __restrict__ hb,
            float* __restrict__ auxp)
{
  const int i4 = blockIdx.x * 256 + threadIdx.x;
  const int e  = i4 << 2;
  const int b = e >> 10;                  // H = 1024
  const int c = e & 1023;
  const unsigned short* g = gi + (long)b * gistride + c;
  const ushort4 a0 = *(const ushort4*)(g);
  const ushort4 a1 = *(const ushort4*)(g + HH);
  const ushort4 a2 = *(const ushort4*)(g + 2 * HH);
  const unsigned short* gg = gh + (long)b * G3 + c;
  const ushort4 b0 = *(const ushort4*)(gg);
  const ushort4 b1 = *(const ushort4*)(gg + HH);
  const ushort4 b2 = *(const ushort4*)(gg + 2 * HH);
  const f32x4 ir  = f32x4{bf2f(a0.x), bf2f(a0.y), bf2f(a0.z), bf2f(a0.w)};
  const f32x4 iz  = f32x4{bf2f(a1.x), bf2f(a1.y), bf2f(a1.z), bf2f(a1.w)};
  const f32x4 inn = f32x4{bf2f(a2.x), bf2f(a2.y), bf2f(a2.z), bf2f(a2.w)};
  const f32x4 hr  = f32x4{bf2f(b0.x), bf2f(b0.y), bf2f(b0.z), bf2f(b0.w)};
  const f32x4 hz  = f32x4{bf2f(b1.x), bf2f(b1.y), bf2f(b1.z), bf2f(b1.w)};
  const f32x4 hn  = f32x4{bf2f(b2.x), bf2f(b2.y), bf2f(b2.z), bf2f(b2.w)};
  const ushort4 ho = *(const ushort4*)(hb + e);
  const f32x4 h = f32x4{bf2f(ho.x), bf2f(ho.y), bf2f(ho.z), bf2f(ho.w)};
  f32x4 hnew;
  float vsum = 0.f;
#pragma unroll
  for (int j = 0; j < 4; ++j) {
    const float r = 1.f / (1.f + __expf(-(ir[j] + hr[j])));
    const float z = 1.f / (1.f + __expf(-(iz[j] + hz[j])));
    const float n = tanhf(inn[j] + r * hn[j]);
    hnew[j] = (1.f - z) * n + z * h[j];
    vsum += hnew[j] * hnew[j];
  }
  ushort4 o;
  o.x = f2bf(hnew[0]); o.y = f2bf(hnew[1]); o.z = f2bf(hnew[2]); o.w = f2bf(hnew[3]);
  *(ushort4*)(hb + e) = o;
  if (auxp != nullptr) {
#pragma unroll
    for (int off = 32; off > 0; off >>= 1) vsum += __shfl_down(vsum, off);
    __shared__ float wsum[4];
    if ((threadIdx.x & 63) == 0) wsum[threadIdx.x >> 6] = vsum;
    __syncthreads();
    if (threadIdx.x == 0) auxp[blockIdx.x] = wsum[0] + wsum[1] + wsum[2] + wsum[3];
  }
}

__global__ __launch_bounds__(256)
void aux_reduce(const float* __restrict__ p, int n, float* __restrict__ out, float scale) {
  float s = 0.f;
  for (int i = threadIdx.x; i < n; i += 256) s += p[i];
#pragma unroll
  for (int off = 32; off > 0; off >>= 1) s += __shfl_down(s, off);
  __shared__ float wsum[4];
  if ((threadIdx.x & 63) == 0) wsum[threadIdx.x >> 6] = s;
  __syncthreads();
  if (threadIdx.x == 0) out[0] = (wsum[0] + wsum[1] + wsum[2] + wsum[3]) * scale;
}

extern "C" void kernel_launch(void* const* d_in, const int* in_sizes, int n_in,
                              void* d_out, int out_size, void* d_ws, size_t ws_size,
                              hipStream_t stream) {
  const float* x    = (const float*)d_in[0];
  const float* Wih1 = (const float*)d_in[1];
  const float* Whh1 = (const float*)d_in[2];
  const float* bih1 = (const float*)d_in[3];
  const float* bhh1 = (const float*)d_in[4];
  const float* Wih2 = (const float*)d_in[5];
  const float* Whh2 = (const float*)d_in[6];
  const float* bih2 = (const float*)d_in[7];
  const float* bhh2 = (const float*)d_in[8];
  const float* Wo1  = (const float*)d_in[9];
  const float* bo1  = (const float*)d_in[10];
  const float* Wo2  = (const float*)d_in[11];
  const float* bo2  = (const float*)d_in[12];

  char* ws = (char*)d_ws;
  size_t off = 0;
  auto alloc = [&](size_t bytes) {
    char* p = ws + off;
    off = (off + bytes + 255) & ~(size_t)255;
    return p;
  };

  unsigned short* xbT   = (unsigned short*)alloc((size_t)BB * TT * INF * 2);  // [T][B][INF]
  unsigned short* wih1b = (unsigned short*)alloc((size_t)G3 * INF * 2);
  unsigned short* whh1b = (unsigned short*)alloc((size_t)G3 * HH * 2);
  unsigned short* wih2b = (unsigned short*)alloc((size_t)G3 * HH * 2);
  unsigned short* whh2b = (unsigned short*)alloc((size_t)G3 * HH * 2);
  unsigned short* wo1b  = (unsigned short*)alloc((size_t)OUTF * HH * 2);
  unsigned short* wo2b  = (unsigned short*)alloc((size_t)OUTF * HH * 2);
  unsigned short* h1b = (unsigned short*)alloc((size_t)BB * HH * 2);
  unsigned short* h2b = (unsigned short*)alloc((size_t)BB * HH * 2);
  unsigned short* gh1 = (unsigned short*)alloc((size_t)BB * G3 * 2);  // also gi2
  unsigned short* gh2 = (unsigned short*)alloc((size_t)BB * G3 * 2);
  float* o1t0 = (float*)alloc((size_t)BB * OUTF * 4);
  float* o1t1 = (float*)alloc((size_t)BB * OUTF * 4);
  float* auxp = (float*)alloc((size_t)TT * (BB * HH / 1024) * 4);
  unsigned short* gi2 = gh1;          // gh1 dead after gate1; stream order safe
  float* o1t[2] = { o1t0, o1t1 };

  // gi1 slabs: hoist as many steps as the workspace allows (>=1 always fits).
  const size_t slab = (size_t)BB * G3 * 2;
  int Th = (int)((ws_size > off ? (ws_size - off) : 0) / (slab + 256));
  if (Th < 1) Th = 1;
  if (Th > TT) Th = TT;
  unsigned short* gi1s = (unsigned short*)alloc((size_t)Th * slab);

  float* aux = (float*)d_out + (size_t)BB * TT * OUTF;

  auto cvt = [&](const float* src, unsigned short* dst, size_t n) {
    int n4 = (int)(n / 4);
    cvt_f32_to_bf16_x4<<<dim3((n4 + 255) / 256), dim3(256), 0, stream>>>(src, dst, n4);
  };
  cvt_x_transpose<<<dim3(BB * TT * INF / 1024), dim3(256), 0, stream>>>(x, xbT);
  cvt(Wih1, wih1b, (size_t)G3 * INF);
  cvt(Whh1, whh1b, (size_t)G3 * HH);
  cvt(Wih2, wih2b, (size_t)G3 * HH);
  cvt(Whh2, whh2b, (size_t)G3 * HH);
  cvt(Wo1,  wo1b,  (size_t)OUTF * HH);
  cvt(Wo2,  wo2b,  (size_t)OUTF * HH);

  hipMemsetAsync(h1b, 0, (size_t)BB * HH * 2, stream);
  hipMemsetAsync(h2b, 0, (size_t)BB * HH * 2, stream);

  const dim3 blk(256);
  const int gateGrid = BB * HH / 1024;   // 4096

  // hoisted gi1 for steps [0, Th): one big GEMM, M = Th*4096
  k_gi1<<<dim3(Th * 768), blk, 0, stream>>>(xbT, wih1b, bih1, gi1s);

  for (int t = 0; t < TT; ++t) {
    const unsigned short* gi1_t;
    if (t < Th) {
      gi1_t = gi1s + (size_t)t * BB * G3;
    } else {
      // recompute into slab 0 (its hoisted content was consumed at t=0)
      k_gi1<<<dim3(768), blk, 0, stream>>>(xbT + (size_t)t * BB * INF,
                                           wih1b, bih1, gi1s);
      gi1_t = gi1s;
    }
    k_gh_dual<<<dim3(1536), blk, 0, stream>>>(h1b, h2b, whh1b, whh2b, bhh1, bhh2, gh1, gh2);
    k_gate<<<dim3(gateGrid), blk, 0, stream>>>(gi1_t, (long)G3, gh1, h1b, nullptr);
    // merged: gi2 | o1(t) | o2(t-1)  (o2 segment only when t > 0)
    k_gi2_o1<<<dim3(t ? 1024 : 896), blk, 0, stream>>>(
        h1b, wih2b, bih2, gi2, wo1b, bo1, o1t[t & 1],
        h2b, wo2b, bo2, o1t[(t + 1) & 1],
        (float*)d_out + (size_t)(t > 0 ? t - 1 : 0) * OUTF);
    k_gate<<<dim3(gateGrid), blk, 0, stream>>>(gi2, (long)G3, gh2, h2b,
                                               auxp + (size_t)t * gateGrid);
  }
  // final output head: h2(T-1) with o1t of step T-1
  k_o2f<<<dim3(128), blk, 0, stream>>>(h2b, wo2b, bo2, o1t[(TT - 1) & 1],
                                       (float*)d_out + (size_t)(TT - 1) * OUTF);
  aux_reduce<<<dim3(1), blk, 0, stream>>>(auxp, TT * gateGrid, aux,
                                          1.f / ((float)BB * (float)HH));
}

// Round 14
// 1414.622 us; speedup vs baseline: 1.1793x; 1.1793x over previous
//
#include <hip/hip_runtime.h>
#include <cstdint>

#define BB   4096
#define TT   7
#define INF  512
#define HH   1024
#define OUTF 512
#define G3   3072   // 3*H

typedef short bf16x8 __attribute__((ext_vector_type(8)));
typedef float f32x4  __attribute__((ext_vector_type(4)));

static __device__ __forceinline__ unsigned short f2bf(float f) {
  unsigned u = __float_as_uint(f);
  unsigned r = ((u >> 16) & 1u) + 0x7FFFu;   // RNE
  return (unsigned short)((u + r) >> 16);
}
static __device__ __forceinline__ float bf2f(unsigned short s) {
  return __uint_as_float(((unsigned)s) << 16);
}

#define GLDS16(gp, lp)                                                        \
  __builtin_amdgcn_global_load_lds(                                           \
      (const __attribute__((address_space(1))) void*)(gp),                    \
      (__attribute__((address_space(3))) void*)(lp), 16, 0, 0)

__device__ __forceinline__ int xcd_swz(int bid, int nwg) {
  return (bid & 7) * (nwg >> 3) + (bid >> 3);   // bijective: nwg % 8 == 0
}

__global__ __launch_bounds__(256)
void cvt_f32_to_bf16_x4(const float* __restrict__ in, unsigned short* __restrict__ out, int n4) {
  int i = blockIdx.x * 256 + threadIdx.x;
  if (i >= n4) return;
  const float4 v = ((const float4*)in)[i];
  ushort4 o;
  o.x = f2bf(v.x); o.y = f2bf(v.y); o.z = f2bf(v.z); o.w = f2bf(v.w);
  ((ushort4*)out)[i] = o;
}

// x [B][T][INF] f32  ->  xbT [T][B][INF] bf16 (both sides coalesced in INF)
__global__ __launch_bounds__(256)
void cvt_x_transpose(const float* __restrict__ in, unsigned short* __restrict__ out) {
  const int i4 = blockIdx.x * 256 + threadIdx.x;   // over B*T*INF/4
  const long e = (long)i4 << 2;
  const int i  = (int)(e & (INF - 1));
  const long bt = e >> 9;                          // b*T + t
  const int t = (int)(bt % TT), b = (int)(bt / TT);
  const float4 v = *(const float4*)(in + e);
  ushort4 o;
  o.x = f2bf(v.x); o.y = f2bf(v.y); o.z = f2bf(v.z); o.w = f2bf(v.w);
  *(ushort4*)(out + ((size_t)t * BB + b) * INF + i) = o;
}

// ---------------------------------------------------------------------------
// r6-verified GEMM core (best measured config): C = A @ W^T + bias.
// bf16 in, f32 acc. BK=64, double-buffered, chunk-XOR swizzle (0 conflicts).
// STAGE(next) before compute; plain __syncthreads schedule.
// mode: 0 f32; 1 f32 tanh; 2 f32 tanh+add; 3 bf16.
// NOTE: exactly ONE gemm_core call per kernel (single __shared__ instance).
// ---------------------------------------------------------------------------
template<int BM, int BN, int WM, int WN, int GN>
__device__ __forceinline__ void gemm_core(
    const unsigned short* __restrict__ A, long lda, long bm,
    const unsigned short* __restrict__ Wp, long ldw, int K,
    const float* __restrict__ biasp,
    void* __restrict__ Cp, long ldc,
    const float* __restrict__ addp, long ldadd, int mode)
{
  constexpr int ABUF = BM * 64;
  constexpr int WBUF = BN * 64;
  constexpr int AR = (BM * 8) / 256;
  constexpr int WR = (BN * 8) / 256;
  __shared__ __attribute__((aligned(16))) unsigned short sm[2 * (ABUF + WBUF)];
  unsigned short* As = sm;
  unsigned short* Ws = sm + 2 * ABUF;
  __attribute__((address_space(3))) unsigned short* lAs =
      (__attribute__((address_space(3))) unsigned short*)As;
  __attribute__((address_space(3))) unsigned short* lWs =
      (__attribute__((address_space(3))) unsigned short*)Ws;

  const int tid  = threadIdx.x;
  const int lane = tid & 63;
  const int wid  = tid >> 6;
  const int wr = (wid / GN) * (WM * 16);
  const int wc = (wid % GN) * (WN * 16);
  const int fr = lane & 15;
  const int q2 = lane >> 4;

  const unsigned short* gpa[AR];
  const unsigned short* gpw[WR];
  int lofa[AR], lofw[WR];
#pragma unroll
  for (int r = 0; r < AR; ++r) {
    const int id = r * 256 + tid;
    const int row = id >> 3, cc = id & 7;
    gpa[r] = A + (bm + row) * lda + (cc ^ (row & 7)) * 8;
    lofa[r] = id * 8;
  }
#pragma unroll
  for (int r = 0; r < WR; ++r) {
    const int id = r * 256 + tid;
    const int row = id >> 3, cc = id & 7;
    gpw[r] = Wp + (long)row * ldw + (cc ^ (row & 7)) * 8;
    lofw[r] = id * 8;
  }

#define STAGE(buf, kt) do {                                                   \
    _Pragma("unroll")                                                         \
    for (int r = 0; r < AR; ++r) GLDS16(gpa[r] + (kt), lAs + (buf) * ABUF + lofa[r]); \
    _Pragma("unroll")                                                         \
    for (int r = 0; r < WR; ++r) GLDS16(gpw[r] + (kt), lWs + (buf) * WBUF + lofw[r]); \
  } while (0)

  f32x4 acc[WM][WN] = {};
  STAGE(0, 0);
  __syncthreads();
  const int NK = K >> 6;
  for (int it = 0; it < NK; ++it) {
    const int cur = it & 1;
    if (it + 1 < NK) STAGE(cur ^ 1, (it + 1) << 6);
#pragma unroll
    for (int ks = 0; ks < 2; ++ks) {
      bf16x8 af[WM], wf[WN];
#pragma unroll
      for (int i = 0; i < WM; ++i) {
        const int row = wr + i * 16 + fr;
        const int ch  = (ks * 4 + q2) ^ (row & 7);
        af[i] = *(const bf16x8*)&As[cur * ABUF + row * 64 + ch * 8];
      }
#pragma unroll
      for (int i = 0; i < WN; ++i) {
        const int row = wc + i * 16 + fr;
        const int ch  = (ks * 4 + q2) ^ (row & 7);
        wf[i] = *(const bf16x8*)&Ws[cur * WBUF + row * 64 + ch * 8];
      }
#pragma unroll
      for (int mi = 0; mi < WM; ++mi)
#pragma unroll
        for (int ni = 0; ni < WN; ++ni)
          acc[mi][ni] = __builtin_amdgcn_mfma_f32_16x16x32_bf16(af[mi], wf[ni], acc[mi][ni], 0, 0, 0);
    }
    __syncthreads();
  }
#undef STAGE

  const int q = lane >> 4;
#pragma unroll
  for (int ni = 0; ni < WN; ++ni) {
    const int col = wc + ni * 16 + fr;
    const float bv = biasp[col];
#pragma unroll
    for (int mi = 0; mi < WM; ++mi) {
      const long row = bm + wr + mi * 16 + q * 4;
#pragma unroll
      for (int j = 0; j < 4; ++j) {
        const float v = acc[mi][ni][j] + bv;
        if (mode == 0)      ((float*)Cp)[(row + j) * ldc + col] = v;
        else if (mode == 1) ((float*)Cp)[(row + j) * ldc + col] = tanhf(v);
        else if (mode == 2) ((float*)Cp)[(row + j) * ldc + col] = tanhf(v) + addp[(row + j) * ldadd + col];
        else                ((unsigned short*)Cp)[(row + j) * ldc + col] = f2bf(v);
      }
    }
  }
}

// gi1 (bf16 out, bias incl.). by-FAST decode: each XCD's contiguous swizzle
// chunk covers all 24 W-panels x few bx row-slabs -> x localized per XCD
// (fixes r12's 8x x-overfetch: FETCH 250 MB vs ~70 ideal). grid = nbx*24.
__global__ __launch_bounds__(256)
void k_gi1(const unsigned short* __restrict__ A,
           const unsigned short* __restrict__ W, const float* __restrict__ bias,
           unsigned short* __restrict__ C)
{
  const int wg = xcd_swz(blockIdx.x, gridDim.x);
  const int by = wg % 24, bx = wg / 24;
  gemm_core<128,128,4,4,2>(A, INF, (long)bx * 128, W + (long)by * 128 * INF,
                           INF, INF, bias + by * 128, C + by * 128, G3, nullptr, 0, 3);
}

// gh1 = h1 @ Whh1^T and gh2 = h2 @ Whh2^T in one 1536-block dispatch (bf16 out)
__global__ __launch_bounds__(256)
void k_gh_dual(const unsigned short* __restrict__ h1b, const unsigned short* __restrict__ h2b,
               const unsigned short* __restrict__ W1, const unsigned short* __restrict__ W2,
               const float* __restrict__ b1, const float* __restrict__ b2,
               unsigned short* __restrict__ gh1, unsigned short* __restrict__ gh2)
{
  const int wg = xcd_swz(blockIdx.x, gridDim.x);   // 1536
  const int bx = wg % 32;
  const int by = (wg / 32) % 24;
  const int z  = wg / (32 * 24);
  const unsigned short* Aa = z ? h2b : h1b;
  const unsigned short* Ww = (z ? W2 : W1) + (long)by * 128 * HH;
  const float* bias = (z ? b2 : b1) + by * 128;
  unsigned short* C = (z ? gh2 : gh1) + by * 128;
  gemm_core<128,128,4,4,2>(Aa, HH, (long)bx * 128, Ww, HH, HH, bias, C, G3, nullptr, 0, 3);
}

// gi2 = h1 @ Wih2^T (bf16) and o1t = tanh(h1 @ Wo1^T + bo1) (f32), one call site
__global__ __launch_bounds__(256)
void k_gi2_o1(const unsigned short* __restrict__ h1b,
              const unsigned short* __restrict__ Wih2, const float* __restrict__ bih2,
              unsigned short* __restrict__ gi2,
              const unsigned short* __restrict__ Wo1, const float* __restrict__ bo1,
              float* __restrict__ o1t)
{
  const int wg = xcd_swz(blockIdx.x, gridDim.x);   // 896
  const int bx = wg % 32;
  const int by = wg / 32;
  const bool g = (by < 24);
  const int bo = by - 24;
  const unsigned short* Ww = g ? (Wih2 + (long)by * 128 * HH) : (Wo1 + (long)bo * 128 * HH);
  const float* bias        = g ? (bih2 + by * 128)            : (bo1 + bo * 128);
  void* C                  = g ? (void*)(gi2 + by * 128)      : (void*)(o1t + bo * 128);
  const long ldc           = g ? (long)G3 : (long)OUTF;
  gemm_core<128,128,4,4,2>(h1b, HH, (long)bx * 128, Ww, HH, HH, bias, C, ldc,
                           nullptr, 0, g ? 3 : 1);
}

// out[b,t,:] = tanh(h2 @ Wo2^T + bo2) + o1t   (64x64 tiles, 512 blocks)
__global__ __launch_bounds__(256)
void k_o2_out(const unsigned short* __restrict__ h2b,
              const unsigned short* __restrict__ Wo2, const float* __restrict__ bo2,
              const float* __restrict__ o1t, float* __restrict__ outp)
{
  const int wg = xcd_swz(blockIdx.x, gridDim.x);   // 512
  const int bx = wg % 64;
  const int by = wg / 64;
  gemm_core<64,64,2,2,2>(h2b, HH, (long)bx * 64, Wo2 + (long)by * 64 * HH, HH, HH,
                         bo2 + by * 64, outp + by * 64, (long)TT * OUTF,
                         o1t + by * 64, OUTF, 2);
}

// GRU gate: h = (1-z)*n + z*h_old. gi, gh bf16; recurrence on bf16 hb (in-place).
__global__ __launch_bounds__(256)
void k_gate(const unsigned short* __restrict__ gi, long gistride,
            const unsigned short* __restrict__ gh,
            unsigned short* __restrict__ hb,
            float* __restrict__ auxp)
{
  const int i4 = blockIdx.x * 256 + threadIdx.x;
  const int e  = i4 << 2;
  const int b = e >> 10;                  // H = 1024
  const int c = e & 1023;
  const unsigned short* g = gi + (long)b * gistride + c;
  const ushort4 a0 = *(const ushort4*)(g);
  const ushort4 a1 = *(const ushort4*)(g + HH);
  const ushort4 a2 = *(const ushort4*)(g + 2 * HH);
  const unsigned short* gg = gh + (long)b * G3 + c;
  const ushort4 b0 = *(const ushort4*)(gg);
  const ushort4 b1 = *(const ushort4*)(gg + HH);
  const ushort4 b2 = *(const ushort4*)(gg + 2 * HH);
  const f32x4 ir  = f32x4{bf2f(a0.x), bf2f(a0.y), bf2f(a0.z), bf2f(a0.w)};
  const f32x4 iz  = f32x4{bf2f(a1.x), bf2f(a1.y), bf2f(a1.z), bf2f(a1.w)};
  const f32x4 inn = f32x4{bf2f(a2.x), bf2f(a2.y), bf2f(a2.z), bf2f(a2.w)};
  const f32x4 hr  = f32x4{bf2f(b0.x), bf2f(b0.y), bf2f(b0.z), bf2f(b0.w)};
  const f32x4 hz  = f32x4{bf2f(b1.x), bf2f(b1.y), bf2f(b1.z), bf2f(b1.w)};
  const f32x4 hn  = f32x4{bf2f(b2.x), bf2f(b2.y), bf2f(b2.z), bf2f(b2.w)};
  const ushort4 ho = *(const ushort4*)(hb + e);
  const f32x4 h = f32x4{bf2f(ho.x), bf2f(ho.y), bf2f(ho.z), bf2f(ho.w)};
  f32x4 hnew;
  float vsum = 0.f;
#pragma unroll
  for (int j = 0; j < 4; ++j) {
    const float r = 1.f / (1.f + __expf(-(ir[j] + hr[j])));
    const float z = 1.f / (1.f + __expf(-(iz[j] + hz[j])));
    const float n = tanhf(inn[j] + r * hn[j]);
    hnew[j] = (1.f - z) * n + z * h[j];
    vsum += hnew[j] * hnew[j];
  }
  ushort4 o;
  o.x = f2bf(hnew[0]); o.y = f2bf(hnew[1]); o.z = f2bf(hnew[2]); o.w = f2bf(hnew[3]);
  *(ushort4*)(hb + e) = o;
  if (auxp != nullptr) {
#pragma unroll
    for (int off = 32; off > 0; off >>= 1) vsum += __shfl_down(vsum, off);
    __shared__ float wsum[4];
    if ((threadIdx.x & 63) == 0) wsum[threadIdx.x >> 6] = vsum;
    __syncthreads();
    if (threadIdx.x == 0) auxp[blockIdx.x] = wsum[0] + wsum[1] + wsum[2] + wsum[3];
  }
}

__global__ __launch_bounds__(256)
void aux_reduce(const float* __restrict__ p, int n, float* __restrict__ out, float scale) {
  float s = 0.f;
  for (int i = threadIdx.x; i < n; i += 256) s += p[i];
#pragma unroll
  for (int off = 32; off > 0; off >>= 1) s += __shfl_down(s, off);
  __shared__ float wsum[4];
  if ((threadIdx.x & 63) == 0) wsum[threadIdx.x >> 6] = s;
  __syncthreads();
  if (threadIdx.x == 0) out[0] = (wsum[0] + wsum[1] + wsum[2] + wsum[3]) * scale;
}

extern "C" void kernel_launch(void* const* d_in, const int* in_sizes, int n_in,
                              void* d_out, int out_size, void* d_ws, size_t ws_size,
                              hipStream_t stream) {
  const float* x    = (const float*)d_in[0];
  const float* Wih1 = (const float*)d_in[1];
  const float* Whh1 = (const float*)d_in[2];
  const float* bih1 = (const float*)d_in[3];
  const float* bhh1 = (const float*)d_in[4];
  const float* Wih2 = (const float*)d_in[5];
  const float* Whh2 = (const float*)d_in[6];
  const float* bih2 = (const float*)d_in[7];
  const float* bhh2 = (const float*)d_in[8];
  const float* Wo1  = (const float*)d_in[9];
  const float* bo1  = (const float*)d_in[10];
  const float* Wo2  = (const float*)d_in[11];
  const float* bo2  = (const float*)d_in[12];

  char* ws = (char*)d_ws;
  size_t off = 0;
  auto alloc = [&](size_t bytes) {
    char* p = ws + off;
    off = (off + bytes + 255) & ~(size_t)255;
    return p;
  };

  unsigned short* xbT   = (unsigned short*)alloc((size_t)BB * TT * INF * 2);  // [T][B][INF]
  unsigned short* wih1b = (unsigned short*)alloc((size_t)G3 * INF * 2);
  unsigned short* whh1b = (unsigned short*)alloc((size_t)G3 * HH * 2);
  unsigned short* wih2b = (unsigned short*)alloc((size_t)G3 * HH * 2);
  unsigned short* whh2b = (unsigned short*)alloc((size_t)G3 * HH * 2);
  unsigned short* wo1b  = (unsigned short*)alloc((size_t)OUTF * HH * 2);
  unsigned short* wo2b  = (unsigned short*)alloc((size_t)OUTF * HH * 2);
  unsigned short* h1b = (unsigned short*)alloc((size_t)BB * HH * 2);
  unsigned short* h2b = (unsigned short*)alloc((size_t)BB * HH * 2);
  unsigned short* gh1 = (unsigned short*)alloc((size_t)BB * G3 * 2);  // also gi2
  unsigned short* gh2 = (unsigned short*)alloc((size_t)BB * G3 * 2);
  float* o1t  = (float*)alloc((size_t)BB * OUTF * 4);
  float* auxp = (float*)alloc((size_t)TT * (BB * HH / 1024) * 4);
  unsigned short* gi2 = gh1;          // gh1 dead after gate1; stream order safe

  // gi1 slabs: hoist as many steps as the workspace allows (>=1 always fits).
  const size_t slab = (size_t)BB * G3 * 2;
  int Th = (int)((ws_size > off ? (ws_size - off) : 0) / (slab + 256));
  if (Th < 1) Th = 1;
  if (Th > TT) Th = TT;
  unsigned short* gi1s = (unsigned short*)alloc((size_t)Th * slab);

  float* aux = (float*)d_out + (size_t)BB * TT * OUTF;

  auto cvt = [&](const float* src, unsigned short* dst, size_t n) {
    int n4 = (int)(n / 4);
    cvt_f32_to_bf16_x4<<<dim3((n4 + 255) / 256), dim3(256), 0, stream>>>(src, dst, n4);
  };
  cvt_x_transpose<<<dim3(BB * TT * INF / 1024), dim3(256), 0, stream>>>(x, xbT);
  cvt(Wih1, wih1b, (size_t)G3 * INF);
  cvt(Whh1, whh1b, (size_t)G3 * HH);
  cvt(Wih2, wih2b, (size_t)G3 * HH);
  cvt(Whh2, whh2b, (size_t)G3 * HH);
  cvt(Wo1,  wo1b,  (size_t)OUTF * HH);
  cvt(Wo2,  wo2b,  (size_t)OUTF * HH);

  hipMemsetAsync(h1b, 0, (size_t)BB * HH * 2, stream);
  hipMemsetAsync(h2b, 0, (size_t)BB * HH * 2, stream);

  const dim3 blk(256);
  const int gateGrid = BB * HH / 1024;   // 4096

  // hoisted gi1 for steps [0, Th): one big GEMM, M = Th*4096
  k_gi1<<<dim3(Th * 768), blk, 0, stream>>>(xbT, wih1b, bih1, gi1s);

  for (int t = 0; t < TT; ++t) {
    const unsigned short* gi1_t;
    if (t < Th) {
      gi1_t = gi1s + (size_t)t * BB * G3;
    } else {
      // recompute into slab 0 (its hoisted content was consumed at t=0)
      k_gi1<<<dim3(768), blk, 0, stream>>>(xbT + (size_t)t * BB * INF,
                                           wih1b, bih1, gi1s);
      gi1_t = gi1s;
    }
    k_gh_dual<<<dim3(1536), blk, 0, stream>>>(h1b, h2b, whh1b, whh2b, bhh1, bhh2, gh1, gh2);
    k_gate<<<dim3(gateGrid), blk, 0, stream>>>(gi1_t, (long)G3, gh1, h1b, nullptr);
    k_gi2_o1<<<dim3(896), blk, 0, stream>>>(h1b, wih2b, bih2, gi2, wo1b, bo1, o1t);
    k_gate<<<dim3(gateGrid), blk, 0, stream>>>(gi2, (long)G3, gh2, h2b,
                                               auxp + (size_t)t * gateGrid);
    k_o2_out<<<dim3(512), blk, 0, stream>>>(h2b, wo2b, bo2, o1t,
                                            (float*)d_out + (size_t)t * OUTF);
  }
  aux_reduce<<<dim3(1), blk, 0, stream>>>(auxp, TT * gateGrid, aux,
                                          1.f / ((float)BB * (float)HH));
}

// Round 15
// 1340.553 us; speedup vs baseline: 1.2445x; 1.0553x over previous
//
#include <hip/hip_runtime.h>
#include <cstdint>

#define BB   4096
#define TT   7
#define INF  512
#define HH   1024
#define OUTF 512
#define G3   3072   // 3*H

typedef short bf16x8 __attribute__((ext_vector_type(8)));
typedef float f32x4  __attribute__((ext_vector_type(4)));

static __device__ __forceinline__ unsigned short f2bf(float f) {
  unsigned u = __float_as_uint(f);
  unsigned r = ((u >> 16) & 1u) + 0x7FFFu;   // RNE
  return (unsigned short)((u + r) >> 16);
}
static __device__ __forceinline__ float bf2f(unsigned short s) {
  return __uint_as_float(((unsigned)s) << 16);
}

#define GLDS16(gp, lp)                                                        \
  __builtin_amdgcn_global_load_lds(                                           \
      (const __attribute__((address_space(1))) void*)(gp),                    \
      (__attribute__((address_space(3))) void*)(lp), 16, 0, 0)

__device__ __forceinline__ int xcd_swz(int bid, int nwg) {
  return (bid & 7) * (nwg >> 3) + (bid >> 3);   // bijective: nwg % 8 == 0
}

__global__ __launch_bounds__(256)
void cvt_f32_to_bf16_x4(const float* __restrict__ in, unsigned short* __restrict__ out, int n4) {
  int i = blockIdx.x * 256 + threadIdx.x;
  if (i >= n4) return;
  const float4 v = ((const float4*)in)[i];
  ushort4 o;
  o.x = f2bf(v.x); o.y = f2bf(v.y); o.z = f2bf(v.z); o.w = f2bf(v.w);
  ((ushort4*)out)[i] = o;
}

// x [B][T][INF] f32  ->  xbT [T][B][INF] bf16 (both sides coalesced in INF)
__global__ __launch_bounds__(256)
void cvt_x_transpose(const float* __restrict__ in, unsigned short* __restrict__ out) {
  const int i4 = blockIdx.x * 256 + threadIdx.x;   // over B*T*INF/4
  const long e = (long)i4 << 2;
  const int i  = (int)(e & (INF - 1));
  const long bt = e >> 9;                          // b*T + t
  const int t = (int)(bt % TT), b = (int)(bt / TT);
  const float4 v = *(const float4*)(in + e);
  ushort4 o;
  o.x = f2bf(v.x); o.y = f2bf(v.y); o.z = f2bf(v.z); o.w = f2bf(v.w);
  *(ushort4*)(out + ((size_t)t * BB + b) * INF + i) = o;
}

// t = 0: h == 0, so gh = 0 @ Whh^T + bhh = bias broadcast. Writing f2bf(bias)
// is bit-identical to the mode-3 GEMM epilogue f2bf(0 + bias) at ~1/8 cost.
__global__ __launch_bounds__(256)
void k_bias_fill(const float* __restrict__ b1, const float* __restrict__ b2,
                 unsigned short* __restrict__ gh1, unsigned short* __restrict__ gh2)
{
  const long e = ((long)blockIdx.x * 256 + threadIdx.x) << 3;  // 8 elems/thread
  const int col = (int)(e % G3);                  // 8-chunk never crosses a row
  const float4 v1a = *(const float4*)(b1 + col);
  const float4 v1b = *(const float4*)(b1 + col + 4);
  const float4 v2a = *(const float4*)(b2 + col);
  const float4 v2b = *(const float4*)(b2 + col + 4);
  ushort4 o;
  o.x = f2bf(v1a.x); o.y = f2bf(v1a.y); o.z = f2bf(v1a.z); o.w = f2bf(v1a.w);
  *(ushort4*)(gh1 + e) = o;
  o.x = f2bf(v1b.x); o.y = f2bf(v1b.y); o.z = f2bf(v1b.z); o.w = f2bf(v1b.w);
  *(ushort4*)(gh1 + e + 4) = o;
  o.x = f2bf(v2a.x); o.y = f2bf(v2a.y); o.z = f2bf(v2a.z); o.w = f2bf(v2a.w);
  *(ushort4*)(gh2 + e) = o;
  o.x = f2bf(v2b.x); o.y = f2bf(v2b.y); o.z = f2bf(v2b.z); o.w = f2bf(v2b.w);
  *(ushort4*)(gh2 + e + 4) = o;
}

// ---------------------------------------------------------------------------
// r6-verified GEMM core (best measured config): C = A @ W^T + bias.
// bf16 in, f32 acc. BK=64, double-buffered, chunk-XOR swizzle (0 conflicts).
// STAGE(next) before compute; plain __syncthreads schedule.
// mode: 0 f32; 1 f32 tanh; 2 f32 tanh+add; 3 bf16.
// NOTE: exactly ONE gemm_core call per kernel (single __shared__ instance).
// ---------------------------------------------------------------------------
template<int BM, int BN, int WM, int WN, int GN>
__device__ __forceinline__ void gemm_core(
    const unsigned short* __restrict__ A, long lda, long bm,
    const unsigned short* __restrict__ Wp, long ldw, int K,
    const float* __restrict__ biasp,
    void* __restrict__ Cp, long ldc,
    const float* __restrict__ addp, long ldadd, int mode)
{
  constexpr int ABUF = BM * 64;
  constexpr int WBUF = BN * 64;
  constexpr int AR = (BM * 8) / 256;
  constexpr int WR = (BN * 8) / 256;
  __shared__ __attribute__((aligned(16))) unsigned short sm[2 * (ABUF + WBUF)];
  unsigned short* As = sm;
  unsigned short* Ws = sm + 2 * ABUF;
  __attribute__((address_space(3))) unsigned short* lAs =
      (__attribute__((address_space(3))) unsigned short*)As;
  __attribute__((address_space(3))) unsigned short* lWs =
      (__attribute__((address_space(3))) unsigned short*)Ws;

  const int tid  = threadIdx.x;
  const int lane = tid & 63;
  const int wid  = tid >> 6;
  const int wr = (wid / GN) * (WM * 16);
  const int wc = (wid % GN) * (WN * 16);
  const int fr = lane & 15;
  const int q2 = lane >> 4;

  const unsigned short* gpa[AR];
  const unsigned short* gpw[WR];
  int lofa[AR], lofw[WR];
#pragma unroll
  for (int r = 0; r < AR; ++r) {
    const int id = r * 256 + tid;
    const int row = id >> 3, cc = id & 7;
    gpa[r] = A + (bm + row) * lda + (cc ^ (row & 7)) * 8;
    lofa[r] = id * 8;
  }
#pragma unroll
  for (int r = 0; r < WR; ++r) {
    const int id = r * 256 + tid;
    const int row = id >> 3, cc = id & 7;
    gpw[r] = Wp + (long)row * ldw + (cc ^ (row & 7)) * 8;
    lofw[r] = id * 8;
  }

#define STAGE(buf, kt) do {                                                   \
    _Pragma("unroll")                                                         \
    for (int r = 0; r < AR; ++r) GLDS16(gpa[r] + (kt), lAs + (buf) * ABUF + lofa[r]); \
    _Pragma("unroll")                                                         \
    for (int r = 0; r < WR; ++r) GLDS16(gpw[r] + (kt), lWs + (buf) * WBUF + lofw[r]); \
  } while (0)

  f32x4 acc[WM][WN] = {};
  STAGE(0, 0);
  __syncthreads();
  const int NK = K >> 6;
  for (int it = 0; it < NK; ++it) {
    const int cur = it & 1;
    if (it + 1 < NK) STAGE(cur ^ 1, (it + 1) << 6);
#pragma unroll
    for (int ks = 0; ks < 2; ++ks) {
      bf16x8 af[WM], wf[WN];
#pragma unroll
      for (int i = 0; i < WM; ++i) {
        const int row = wr + i * 16 + fr;
        const int ch  = (ks * 4 + q2) ^ (row & 7);
        af[i] = *(const bf16x8*)&As[cur * ABUF + row * 64 + ch * 8];
      }
#pragma unroll
      for (int i = 0; i < WN; ++i) {
        const int row = wc + i * 16 + fr;
        const int ch  = (ks * 4 + q2) ^ (row & 7);
        wf[i] = *(const bf16x8*)&Ws[cur * WBUF + row * 64 + ch * 8];
      }
#pragma unroll
      for (int mi = 0; mi < WM; ++mi)
#pragma unroll
        for (int ni = 0; ni < WN; ++ni)
          acc[mi][ni] = __builtin_amdgcn_mfma_f32_16x16x32_bf16(af[mi], wf[ni], acc[mi][ni], 0, 0, 0);
    }
    __syncthreads();
  }
#undef STAGE

  const int q = lane >> 4;
#pragma unroll
  for (int ni = 0; ni < WN; ++ni) {
    const int col = wc + ni * 16 + fr;
    const float bv = biasp[col];
#pragma unroll
    for (int mi = 0; mi < WM; ++mi) {
      const long row = bm + wr + mi * 16 + q * 4;
#pragma unroll
      for (int j = 0; j < 4; ++j) {
        const float v = acc[mi][ni][j] + bv;
        if (mode == 0)      ((float*)Cp)[(row + j) * ldc + col] = v;
        else if (mode == 1) ((float*)Cp)[(row + j) * ldc + col] = tanhf(v);
        else if (mode == 2) ((float*)Cp)[(row + j) * ldc + col] = tanhf(v) + addp[(row + j) * ldadd + col];
        else                ((unsigned short*)Cp)[(row + j) * ldc + col] = f2bf(v);
      }
    }
  }
}

// gi1 (bf16 out, bias incl.). Hoisted: A = xbT (M = Th*4096, lda = INF),
// gx = Th*32. Per-step: A = xbT + t*BB*INF, gx = 32. (r12 decode: VGPR 112.)
__global__ __launch_bounds__(256)
void k_gi1(const unsigned short* __restrict__ A,
           const unsigned short* __restrict__ W, const float* __restrict__ bias,
           unsigned short* __restrict__ C, int gx)
{
  const int wg = xcd_swz(blockIdx.x, gridDim.x);
  const int bx = wg % gx, by = wg / gx;
  gemm_core<128,128,4,4,2>(A, INF, (long)bx * 128, W + (long)by * 128 * INF,
                           INF, INF, bias + by * 128, C + by * 128, G3, nullptr, 0, 3);
}

// gh1 = h1 @ Whh1^T and gh2 = h2 @ Whh2^T in one 1536-block dispatch (bf16 out)
__global__ __launch_bounds__(256)
void k_gh_dual(const unsigned short* __restrict__ h1b, const unsigned short* __restrict__ h2b,
               const unsigned short* __restrict__ W1, const unsigned short* __restrict__ W2,
               const float* __restrict__ b1, const float* __restrict__ b2,
               unsigned short* __restrict__ gh1, unsigned short* __restrict__ gh2)
{
  const int wg = xcd_swz(blockIdx.x, gridDim.x);   // 1536
  const int bx = wg % 32;
  const int by = (wg / 32) % 24;
  const int z  = wg / (32 * 24);
  const unsigned short* Aa = z ? h2b : h1b;
  const unsigned short* Ww = (z ? W2 : W1) + (long)by * 128 * HH;
  const float* bias = (z ? b2 : b1) + by * 128;
  unsigned short* C = (z ? gh2 : gh1) + by * 128;
  gemm_core<128,128,4,4,2>(Aa, HH, (long)bx * 128, Ww, HH, HH, bias, C, G3, nullptr, 0, 3);
}

// gi2 = h1 @ Wih2^T (bf16) and o1t = tanh(h1 @ Wo1^T + bo1) (f32), one call site
__global__ __launch_bounds__(256)
void k_gi2_o1(const unsigned short* __restrict__ h1b,
              const unsigned short* __restrict__ Wih2, const float* __restrict__ bih2,
              unsigned short* __restrict__ gi2,
              const unsigned short* __restrict__ Wo1, const float* __restrict__ bo1,
              float* __restrict__ o1t)
{
  const int wg = xcd_swz(blockIdx.x, gridDim.x);   // 896
  const int bx = wg % 32;
  const int by = wg / 32;
  const bool g = (by < 24);
  const int bo = by - 24;
  const unsigned short* Ww = g ? (Wih2 + (long)by * 128 * HH) : (Wo1 + (long)bo * 128 * HH);
  const float* bias        = g ? (bih2 + by * 128)            : (bo1 + bo * 128);
  void* C                  = g ? (void*)(gi2 + by * 128)      : (void*)(o1t + bo * 128);
  const long ldc           = g ? (long)G3 : (long)OUTF;
  gemm_core<128,128,4,4,2>(h1b, HH, (long)bx * 128, Ww, HH, HH, bias, C, ldc,
                           nullptr, 0, g ? 3 : 1);
}

// out[b,t,:] = tanh(h2 @ Wo2^T + bo2) + o1t   (64x64 tiles, 512 blocks)
__global__ __launch_bounds__(256)
void k_o2_out(const unsigned short* __restrict__ h2b,
              const unsigned short* __restrict__ Wo2, const float* __restrict__ bo2,
              const float* __restrict__ o1t, float* __restrict__ outp)
{
  const int wg = xcd_swz(blockIdx.x, gridDim.x);   // 512
  const int bx = wg % 64;
  const int by = wg / 64;
  gemm_core<64,64,2,2,2>(h2b, HH, (long)bx * 64, Wo2 + (long)by * 64 * HH, HH, HH,
                         bo2 + by * 64, outp + by * 64, (long)TT * OUTF,
                         o1t + by * 64, OUTF, 2);
}

// GRU gate: h = (1-z)*n + z*h_old. gi, gh bf16; recurrence on bf16 hb (in-place).
__global__ __launch_bounds__(256)
void k_gate(const unsigned short* __restrict__ gi, long gistride,
            const unsigned short* __restrict__ gh,
            unsigned short* __restrict__ hb,
            float* __restrict__ auxp)
{
  const int i4 = blockIdx.x * 256 + threadIdx.x;
  const int e  = i4 << 2;
  const int b = e >> 10;                  // H = 1024
  const int c = e & 1023;
  const unsigned short* g = gi + (long)b * gistride + c;
  const ushort4 a0 = *(const ushort4*)(g);
  const ushort4 a1 = *(const ushort4*)(g + HH);
  const ushort4 a2 = *(const ushort4*)(g + 2 * HH);
  const unsigned short* gg = gh + (long)b * G3 + c;
  const ushort4 b0 = *(const ushort4*)(gg);
  const ushort4 b1 = *(const ushort4*)(gg + HH);
  const ushort4 b2 = *(const ushort4*)(gg + 2 * HH);
  const f32x4 ir  = f32x4{bf2f(a0.x), bf2f(a0.y), bf2f(a0.z), bf2f(a0.w)};
  const f32x4 iz  = f32x4{bf2f(a1.x), bf2f(a1.y), bf2f(a1.z), bf2f(a1.w)};
  const f32x4 inn = f32x4{bf2f(a2.x), bf2f(a2.y), bf2f(a2.z), bf2f(a2.w)};
  const f32x4 hr  = f32x4{bf2f(b0.x), bf2f(b0.y), bf2f(b0.z), bf2f(b0.w)};
  const f32x4 hz  = f32x4{bf2f(b1.x), bf2f(b1.y), bf2f(b1.z), bf2f(b1.w)};
  const f32x4 hn  = f32x4{bf2f(b2.x), bf2f(b2.y), bf2f(b2.z), bf2f(b2.w)};
  const ushort4 ho = *(const ushort4*)(hb + e);
  const f32x4 h = f32x4{bf2f(ho.x), bf2f(ho.y), bf2f(ho.z), bf2f(ho.w)};
  f32x4 hnew;
  float vsum = 0.f;
#pragma unroll
  for (int j = 0; j < 4; ++j) {
    const float r = 1.f / (1.f + __expf(-(ir[j] + hr[j])));
    const float z = 1.f / (1.f + __expf(-(iz[j] + hz[j])));
    const float n = tanhf(inn[j] + r * hn[j]);
    hnew[j] = (1.f - z) * n + z * h[j];
    vsum += hnew[j] * hnew[j];
  }
  ushort4 o;
  o.x = f2bf(hnew[0]); o.y = f2bf(hnew[1]); o.z = f2bf(hnew[2]); o.w = f2bf(hnew[3]);
  *(ushort4*)(hb + e) = o;
  if (auxp != nullptr) {
#pragma unroll
    for (int off = 32; off > 0; off >>= 1) vsum += __shfl_down(vsum, off);
    __shared__ float wsum[4];
    if ((threadIdx.x & 63) == 0) wsum[threadIdx.x >> 6] = vsum;
    __syncthreads();
    if (threadIdx.x == 0) auxp[blockIdx.x] = wsum[0] + wsum[1] + wsum[2] + wsum[3];
  }
}

__global__ __launch_bounds__(256)
void aux_reduce(const float* __restrict__ p, int n, float* __restrict__ out, float scale) {
  float s = 0.f;
  for (int i = threadIdx.x; i < n; i += 256) s += p[i];
#pragma unroll
  for (int off = 32; off > 0; off >>= 1) s += __shfl_down(s, off);
  __shared__ float wsum[4];
  if ((threadIdx.x & 63) == 0) wsum[threadIdx.x >> 6] = s;
  __syncthreads();
  if (threadIdx.x == 0) out[0] = (wsum[0] + wsum[1] + wsum[2] + wsum[3]) * scale;
}

extern "C" void kernel_launch(void* const* d_in, const int* in_sizes, int n_in,
                              void* d_out, int out_size, void* d_ws, size_t ws_size,
                              hipStream_t stream) {
  const float* x    = (const float*)d_in[0];
  const float* Wih1 = (const float*)d_in[1];
  const float* Whh1 = (const float*)d_in[2];
  const float* bih1 = (const float*)d_in[3];
  const float* bhh1 = (const float*)d_in[4];
  const float* Wih2 = (const float*)d_in[5];
  const float* Whh2 = (const float*)d_in[6];
  const float* bih2 = (const float*)d_in[7];
  const float* bhh2 = (const float*)d_in[8];
  const float* Wo1  = (const float*)d_in[9];
  const float* bo1  = (const float*)d_in[10];
  const float* Wo2  = (const float*)d_in[11];
  const float* bo2  = (const float*)d_in[12];

  char* ws = (char*)d_ws;
  size_t off = 0;
  auto alloc = [&](size_t bytes) {
    char* p = ws + off;
    off = (off + bytes + 255) & ~(size_t)255;
    return p;
  };

  unsigned short* xbT   = (unsigned short*)alloc((size_t)BB * TT * INF * 2);  // [T][B][INF]
  unsigned short* wih1b = (unsigned short*)alloc((size_t)G3 * INF * 2);
  unsigned short* whh1b = (unsigned short*)alloc((size_t)G3 * HH * 2);
  unsigned short* wih2b = (unsigned short*)alloc((size_t)G3 * HH * 2);
  unsigned short* whh2b = (unsigned short*)alloc((size_t)G3 * HH * 2);
  unsigned short* wo1b  = (unsigned short*)alloc((size_t)OUTF * HH * 2);
  unsigned short* wo2b  = (unsigned short*)alloc((size_t)OUTF * HH * 2);
  unsigned short* h1b = (unsigned short*)alloc((size_t)BB * HH * 2);
  unsigned short* h2b = (unsigned short*)alloc((size_t)BB * HH * 2);
  unsigned short* gh1 = (unsigned short*)alloc((size_t)BB * G3 * 2);  // also gi2
  unsigned short* gh2 = (unsigned short*)alloc((size_t)BB * G3 * 2);
  float* o1t  = (float*)alloc((size_t)BB * OUTF * 4);
  float* auxp = (float*)alloc((size_t)TT * (BB * HH / 1024) * 4);
  unsigned short* gi2 = gh1;          // gh1 dead after gate1; stream order safe

  // gi1 slabs: hoist as many steps as the workspace allows (>=1 always fits).
  const size_t slab = (size_t)BB * G3 * 2;
  int Th = (int)((ws_size > off ? (ws_size - off) : 0) / (slab + 256));
  if (Th < 1) Th = 1;
  if (Th > TT) Th = TT;
  unsigned short* gi1s = (unsigned short*)alloc((size_t)Th * slab);

  float* aux = (float*)d_out + (size_t)BB * TT * OUTF;

  auto cvt = [&](const float* src, unsigned short* dst, size_t n) {
    int n4 = (int)(n / 4);
    cvt_f32_to_bf16_x4<<<dim3((n4 + 255) / 256), dim3(256), 0, stream>>>(src, dst, n4);
  };
  cvt_x_transpose<<<dim3(BB * TT * INF / 1024), dim3(256), 0, stream>>>(x, xbT);
  cvt(Wih1, wih1b, (size_t)G3 * INF);
  cvt(Whh1, whh1b, (size_t)G3 * HH);
  cvt(Wih2, wih2b, (size_t)G3 * HH);
  cvt(Whh2, whh2b, (size_t)G3 * HH);
  cvt(Wo1,  wo1b,  (size_t)OUTF * HH);
  cvt(Wo2,  wo2b,  (size_t)OUTF * HH);

  hipMemsetAsync(h1b, 0, (size_t)BB * HH * 2, stream);
  hipMemsetAsync(h2b, 0, (size_t)BB * HH * 2, stream);

  const dim3 blk(256);
  const int gateGrid = BB * HH / 1024;   // 4096

  // hoisted gi1 for steps [0, Th): one big GEMM, M = Th*4096
  k_gi1<<<dim3(Th * 768), blk, 0, stream>>>(xbT, wih1b, bih1, gi1s, Th * 32);

  for (int t = 0; t < TT; ++t) {
    const unsigned short* gi1_t;
    if (t < Th) {
      gi1_t = gi1s + (size_t)t * BB * G3;
    } else {
      // recompute into slab 0 (its hoisted content was consumed at t=0)
      k_gi1<<<dim3(768), blk, 0, stream>>>(xbT + (size_t)t * BB * INF,
                                           wih1b, bih1, gi1s, 32);
      gi1_t = gi1s;
    }
    if (t == 0) {
      // h == 0: gh = bias broadcast, bit-identical to the GEMM at ~1/8 cost
      k_bias_fill<<<dim3(BB * G3 / 2048), blk, 0, stream>>>(bhh1, bhh2, gh1, gh2);
    } else {
      k_gh_dual<<<dim3(1536), blk, 0, stream>>>(h1b, h2b, whh1b, whh2b, bhh1, bhh2, gh1, gh2);
    }
    k_gate<<<dim3(gateGrid), blk, 0, stream>>>(gi1_t, (long)G3, gh1, h1b, nullptr);
    k_gi2_o1<<<dim3(896), blk, 0, stream>>>(h1b, wih2b, bih2, gi2, wo1b, bo1, o1t);
    k_gate<<<dim3(gateGrid), blk, 0, stream>>>(gi2, (long)G3, gh2, h2b,
                                               auxp + (size_t)t * gateGrid);
    k_o2_out<<<dim3(512), blk, 0, stream>>>(h2b, wo2b, bo2, o1t,
                                            (float*)d_out + (size_t)t * OUTF);
  }
  aux_reduce<<<dim3(1), blk, 0, stream>>>(auxp, TT * gateGrid, aux,
                                          1.f / ((float)BB * (float)HH));
}

// Round 16
// 1336.550 us; speedup vs baseline: 1.2482x; 1.0030x over previous
//
#include <hip/hip_runtime.h>
#include <cstdint>

#define BB   4096
#define TT   7
#define INF  512
#define HH   1024
#define OUTF 512
#define G3   3072   // 3*H

typedef short bf16x8 __attribute__((ext_vector_type(8)));
typedef float f32x4  __attribute__((ext_vector_type(4)));

static __device__ __forceinline__ unsigned short f2bf(float f) {
  unsigned u = __float_as_uint(f);
  unsigned r = ((u >> 16) & 1u) + 0x7FFFu;   // RNE
  return (unsigned short)((u + r) >> 16);
}
static __device__ __forceinline__ float bf2f(unsigned short s) {
  return __uint_as_float(((unsigned)s) << 16);
}

#define GLDS16(gp, lp)                                                        \
  __builtin_amdgcn_global_load_lds(                                           \
      (const __attribute__((address_space(1))) void*)(gp),                    \
      (__attribute__((address_space(3))) void*)(lp), 16, 0, 0)

__device__ __forceinline__ int xcd_swz(int bid, int nwg) {
  return (bid & 7) * (nwg >> 3) + (bid >> 3);   // bijective: nwg % 8 == 0
}

__global__ __launch_bounds__(256)
void cvt_f32_to_bf16_x4(const float* __restrict__ in, unsigned short* __restrict__ out, int n4) {
  int i = blockIdx.x * 256 + threadIdx.x;
  if (i >= n4) return;
  const float4 v = ((const float4*)in)[i];
  ushort4 o;
  o.x = f2bf(v.x); o.y = f2bf(v.y); o.z = f2bf(v.z); o.w = f2bf(v.w);
  ((ushort4*)out)[i] = o;
}

// x [B][T][INF] f32  ->  xbT [T][B][INF] bf16 (both sides coalesced in INF)
__global__ __launch_bounds__(256)
void cvt_x_transpose(const float* __restrict__ in, unsigned short* __restrict__ out) {
  const int i4 = blockIdx.x * 256 + threadIdx.x;   // over B*T*INF/4
  const long e = (long)i4 << 2;
  const int i  = (int)(e & (INF - 1));
  const long bt = e >> 9;                          // b*T + t
  const int t = (int)(bt % TT), b = (int)(bt / TT);
  const float4 v = *(const float4*)(in + e);
  ushort4 o;
  o.x = f2bf(v.x); o.y = f2bf(v.y); o.z = f2bf(v.z); o.w = f2bf(v.w);
  *(ushort4*)(out + ((size_t)t * BB + b) * INF + i) = o;
}

// ---------------------------------------------------------------------------
// r6-verified GEMM core (best measured config): C = A @ W^T + bias.
// bf16 in, f32 acc. BK=64, double-buffered, chunk-XOR swizzle (0 conflicts).
// STAGE(next) before compute; plain __syncthreads schedule.
// mode: 0 f32; 1 f32 tanh; 2 f32 tanh+add; 3 bf16.
// NOTE: exactly ONE gemm_core call per kernel (single __shared__ instance).
// ---------------------------------------------------------------------------
template<int BM, int BN, int WM, int WN, int GN>
__device__ __forceinline__ void gemm_core(
    const unsigned short* __restrict__ A, long lda, long bm,
    const unsigned short* __restrict__ Wp, long ldw, int K,
    const float* __restrict__ biasp,
    void* __restrict__ Cp, long ldc,
    const float* __restrict__ addp, long ldadd, int mode)
{
  constexpr int ABUF = BM * 64;
  constexpr int WBUF = BN * 64;
  constexpr int AR = (BM * 8) / 256;
  constexpr int WR = (BN * 8) / 256;
  __shared__ __attribute__((aligned(16))) unsigned short sm[2 * (ABUF + WBUF)];
  unsigned short* As = sm;
  unsigned short* Ws = sm + 2 * ABUF;
  __attribute__((address_space(3))) unsigned short* lAs =
      (__attribute__((address_space(3))) unsigned short*)As;
  __attribute__((address_space(3))) unsigned short* lWs =
      (__attribute__((address_space(3))) unsigned short*)Ws;

  const int tid  = threadIdx.x;
  const int lane = tid & 63;
  const int wid  = tid >> 6;
  const int wr = (wid / GN) * (WM * 16);
  const int wc = (wid % GN) * (WN * 16);
  const int fr = lane & 15;
  const int q2 = lane >> 4;

  const unsigned short* gpa[AR];
  const unsigned short* gpw[WR];
  int lofa[AR], lofw[WR];
#pragma unroll
  for (int r = 0; r < AR; ++r) {
    const int id = r * 256 + tid;
    const int row = id >> 3, cc = id & 7;
    gpa[r] = A + (bm + row) * lda + (cc ^ (row & 7)) * 8;
    lofa[r] = id * 8;
  }
#pragma unroll
  for (int r = 0; r < WR; ++r) {
    const int id = r * 256 + tid;
    const int row = id >> 3, cc = id & 7;
    gpw[r] = Wp + (long)row * ldw + (cc ^ (row & 7)) * 8;
    lofw[r] = id * 8;
  }

#define STAGE(buf, kt) do {                                                   \
    _Pragma("unroll")                                                         \
    for (int r = 0; r < AR; ++r) GLDS16(gpa[r] + (kt), lAs + (buf) * ABUF + lofa[r]); \
    _Pragma("unroll")                                                         \
    for (int r = 0; r < WR; ++r) GLDS16(gpw[r] + (kt), lWs + (buf) * WBUF + lofw[r]); \
  } while (0)

  f32x4 acc[WM][WN] = {};
  STAGE(0, 0);
  __syncthreads();
  const int NK = K >> 6;
  for (int it = 0; it < NK; ++it) {
    const int cur = it & 1;
    if (it + 1 < NK) STAGE(cur ^ 1, (it + 1) << 6);
#pragma unroll
    for (int ks = 0; ks < 2; ++ks) {
      bf16x8 af[WM], wf[WN];
#pragma unroll
      for (int i = 0; i < WM; ++i) {
        const int row = wr + i * 16 + fr;
        const int ch  = (ks * 4 + q2) ^ (row & 7);
        af[i] = *(const bf16x8*)&As[cur * ABUF + row * 64 + ch * 8];
      }
#pragma unroll
      for (int i = 0; i < WN; ++i) {
        const int row = wc + i * 16 + fr;
        const int ch  = (ks * 4 + q2) ^ (row & 7);
        wf[i] = *(const bf16x8*)&Ws[cur * WBUF + row * 64 + ch * 8];
      }
#pragma unroll
      for (int mi = 0; mi < WM; ++mi)
#pragma unroll
        for (int ni = 0; ni < WN; ++ni)
          acc[mi][ni] = __builtin_amdgcn_mfma_f32_16x16x32_bf16(af[mi], wf[ni], acc[mi][ni], 0, 0, 0);
    }
    __syncthreads();
  }
#undef STAGE

  const int q = lane >> 4;
#pragma unroll
  for (int ni = 0; ni < WN; ++ni) {
    const int col = wc + ni * 16 + fr;
    const float bv = biasp[col];
#pragma unroll
    for (int mi = 0; mi < WM; ++mi) {
      const long row = bm + wr + mi * 16 + q * 4;
#pragma unroll
      for (int j = 0; j < 4; ++j) {
        const float v = acc[mi][ni][j] + bv;
        if (mode == 0)      ((float*)Cp)[(row + j) * ldc + col] = v;
        else if (mode == 1) ((float*)Cp)[(row + j) * ldc + col] = tanhf(v);
        else if (mode == 2) ((float*)Cp)[(row + j) * ldc + col] = tanhf(v) + addp[(row + j) * ldadd + col];
        else                ((unsigned short*)Cp)[(row + j) * ldc + col] = f2bf(v);
      }
    }
  }
}

// gi1 (bf16 out, bias incl.). Hoisted: A = xbT (M = Th*4096, lda = INF),
// gx = Th*32. Per-step: A = xbT + t*BB*INF, gx = 32. (r12 decode: VGPR 112.)
__global__ __launch_bounds__(256)
void k_gi1(const unsigned short* __restrict__ A,
           const unsigned short* __restrict__ W, const float* __restrict__ bias,
           unsigned short* __restrict__ C, int gx)
{
  const int wg = xcd_swz(blockIdx.x, gridDim.x);
  const int bx = wg % gx, by = wg / gx;
  gemm_core<128,128,4,4,2>(A, INF, (long)bx * 128, W + (long)by * 128 * INF,
                           INF, INF, bias + by * 128, C + by * 128, G3, nullptr, 0, 3);
}

// gh1 = h1 @ Whh1^T and gh2 = h2 @ Whh2^T in one 1536-block dispatch (bf16 out)
__global__ __launch_bounds__(256)
void k_gh_dual(const unsigned short* __restrict__ h1b, const unsigned short* __restrict__ h2b,
               const unsigned short* __restrict__ W1, const unsigned short* __restrict__ W2,
               const float* __restrict__ b1, const float* __restrict__ b2,
               unsigned short* __restrict__ gh1, unsigned short* __restrict__ gh2)
{
  const int wg = xcd_swz(blockIdx.x, gridDim.x);   // 1536
  const int bx = wg % 32;
  const int by = (wg / 32) % 24;
  const int z  = wg / (32 * 24);
  const unsigned short* Aa = z ? h2b : h1b;
  const unsigned short* Ww = (z ? W2 : W1) + (long)by * 128 * HH;
  const float* bias = (z ? b2 : b1) + by * 128;
  unsigned short* C = (z ? gh2 : gh1) + by * 128;
  gemm_core<128,128,4,4,2>(Aa, HH, (long)bx * 128, Ww, HH, HH, bias, C, G3, nullptr, 0, 3);
}

// gi2 = h1 @ Wih2^T (bf16) and o1t = tanh(h1 @ Wo1^T + bo1) (f32), one call site
__global__ __launch_bounds__(256)
void k_gi2_o1(const unsigned short* __restrict__ h1b,
              const unsigned short* __restrict__ Wih2, const float* __restrict__ bih2,
              unsigned short* __restrict__ gi2,
              const unsigned short* __restrict__ Wo1, const float* __restrict__ bo1,
              float* __restrict__ o1t)
{
  const int wg = xcd_swz(blockIdx.x, gridDim.x);   // 896
  const int bx = wg % 32;
  const int by = wg / 32;
  const bool g = (by < 24);
  const int bo = by - 24;
  const unsigned short* Ww = g ? (Wih2 + (long)by * 128 * HH) : (Wo1 + (long)bo * 128 * HH);
  const float* bias        = g ? (bih2 + by * 128)            : (bo1 + bo * 128);
  void* C                  = g ? (void*)(gi2 + by * 128)      : (void*)(o1t + bo * 128);
  const long ldc           = g ? (long)G3 : (long)OUTF;
  gemm_core<128,128,4,4,2>(h1b, HH, (long)bx * 128, Ww, HH, HH, bias, C, ldc,
                           nullptr, 0, g ? 3 : 1);
}

// out[b,t,:] = tanh(h2 @ Wo2^T + bo2) + o1t   (64x64 tiles, 512 blocks)
__global__ __launch_bounds__(256)
void k_o2_out(const unsigned short* __restrict__ h2b,
              const unsigned short* __restrict__ Wo2, const float* __restrict__ bo2,
              const float* __restrict__ o1t, float* __restrict__ outp)
{
  const int wg = xcd_swz(blockIdx.x, gridDim.x);   // 512
  const int bx = wg % 64;
  const int by = wg / 64;
  gemm_core<64,64,2,2,2>(h2b, HH, (long)bx * 64, Wo2 + (long)by * 64 * HH, HH, HH,
                         bo2 + by * 64, outp + by * 64, (long)TT * OUTF,
                         o1t + by * 64, OUTF, 2);
}

// GRU gate: h = (1-z)*n + z*h_old. gi bf16; gh bf16 OR (BIAS: t=0) f32 bias
// broadcast with h_old == 0 (gh = 0 @ Whh^T + bhh = bhh exactly).
template<bool BIAS>
__global__ __launch_bounds__(256)
void k_gate(const unsigned short* __restrict__ gi, long gistride,
            const unsigned short* __restrict__ gh, const float* __restrict__ ghb,
            unsigned short* __restrict__ hb,
            float* __restrict__ auxp)
{
  const int i4 = blockIdx.x * 256 + threadIdx.x;
  const int e  = i4 << 2;
  const int b = e >> 10;                  // H = 1024
  const int c = e & 1023;
  const unsigned short* g = gi + (long)b * gistride + c;
  const ushort4 a0 = *(const ushort4*)(g);
  const ushort4 a1 = *(const ushort4*)(g + HH);
  const ushort4 a2 = *(const ushort4*)(g + 2 * HH);
  const f32x4 ir  = f32x4{bf2f(a0.x), bf2f(a0.y), bf2f(a0.z), bf2f(a0.w)};
  const f32x4 iz  = f32x4{bf2f(a1.x), bf2f(a1.y), bf2f(a1.z), bf2f(a1.w)};
  const f32x4 inn = f32x4{bf2f(a2.x), bf2f(a2.y), bf2f(a2.z), bf2f(a2.w)};
  f32x4 hr, hz, hn, h;
  if (BIAS) {
    hr = *(const f32x4*)(ghb + c);
    hz = *(const f32x4*)(ghb + HH + c);
    hn = *(const f32x4*)(ghb + 2 * HH + c);
    h  = f32x4{0.f, 0.f, 0.f, 0.f};
  } else {
    const unsigned short* gg = gh + (long)b * G3 + c;
    const ushort4 b0 = *(const ushort4*)(gg);
    const ushort4 b1 = *(const ushort4*)(gg + HH);
    const ushort4 b2 = *(const ushort4*)(gg + 2 * HH);
    hr = f32x4{bf2f(b0.x), bf2f(b0.y), bf2f(b0.z), bf2f(b0.w)};
    hz = f32x4{bf2f(b1.x), bf2f(b1.y), bf2f(b1.z), bf2f(b1.w)};
    hn = f32x4{bf2f(b2.x), bf2f(b2.y), bf2f(b2.z), bf2f(b2.w)};
    const ushort4 ho = *(const ushort4*)(hb + e);
    h = f32x4{bf2f(ho.x), bf2f(ho.y), bf2f(ho.z), bf2f(ho.w)};
  }
  f32x4 hnew;
  float vsum = 0.f;
#pragma unroll
  for (int j = 0; j < 4; ++j) {
    const float r = 1.f / (1.f + __expf(-(ir[j] + hr[j])));
    const float z = 1.f / (1.f + __expf(-(iz[j] + hz[j])));
    const float n = tanhf(inn[j] + r * hn[j]);
    hnew[j] = (1.f - z) * n + z * h[j];
    vsum += hnew[j] * hnew[j];
  }
  ushort4 o;
  o.x = f2bf(hnew[0]); o.y = f2bf(hnew[1]); o.z = f2bf(hnew[2]); o.w = f2bf(hnew[3]);
  *(ushort4*)(hb + e) = o;
  if (auxp != nullptr) {
#pragma unroll
    for (int off = 32; off > 0; off >>= 1) vsum += __shfl_down(vsum, off);
    __shared__ float wsum[4];
    if ((threadIdx.x & 63) == 0) wsum[threadIdx.x >> 6] = vsum;
    __syncthreads();
    if (threadIdx.x == 0) auxp[blockIdx.x] = wsum[0] + wsum[1] + wsum[2] + wsum[3];
  }
}

__global__ __launch_bounds__(256)
void aux_reduce(const float* __restrict__ p, int n, float* __restrict__ out, float scale) {
  float s = 0.f;
  for (int i = threadIdx.x; i < n; i += 256) s += p[i];
#pragma unroll
  for (int off = 32; off > 0; off >>= 1) s += __shfl_down(s, off);
  __shared__ float wsum[4];
  if ((threadIdx.x & 63) == 0) wsum[threadIdx.x >> 6] = s;
  __syncthreads();
  if (threadIdx.x == 0) out[0] = (wsum[0] + wsum[1] + wsum[2] + wsum[3]) * scale;
}

extern "C" void kernel_launch(void* const* d_in, const int* in_sizes, int n_in,
                              void* d_out, int out_size, void* d_ws, size_t ws_size,
                              hipStream_t stream) {
  const float* x    = (const float*)d_in[0];
  const float* Wih1 = (const float*)d_in[1];
  const float* Whh1 = (const float*)d_in[2];
  const float* bih1 = (const float*)d_in[3];
  const float* bhh1 = (const float*)d_in[4];
  const float* Wih2 = (const float*)d_in[5];
  const float* Whh2 = (const float*)d_in[6];
  const float* bih2 = (const float*)d_in[7];
  const float* bhh2 = (const float*)d_in[8];
  const float* Wo1  = (const float*)d_in[9];
  const float* bo1  = (const float*)d_in[10];
  const float* Wo2  = (const float*)d_in[11];
  const float* bo2  = (const float*)d_in[12];

  char* ws = (char*)d_ws;
  size_t off = 0;
  auto alloc = [&](size_t bytes) {
    char* p = ws + off;
    off = (off + bytes + 255) & ~(size_t)255;
    return p;
  };

  unsigned short* xbT   = (unsigned short*)alloc((size_t)BB * TT * INF * 2);  // [T][B][INF]
  unsigned short* wih1b = (unsigned short*)alloc((size_t)G3 * INF * 2);
  unsigned short* whh1b = (unsigned short*)alloc((size_t)G3 * HH * 2);
  unsigned short* wih2b = (unsigned short*)alloc((size_t)G3 * HH * 2);
  unsigned short* whh2b = (unsigned short*)alloc((size_t)G3 * HH * 2);
  unsigned short* wo1b  = (unsigned short*)alloc((size_t)OUTF * HH * 2);
  unsigned short* wo2b  = (unsigned short*)alloc((size_t)OUTF * HH * 2);
  unsigned short* h1b = (unsigned short*)alloc((size_t)BB * HH * 2);
  unsigned short* h2b = (unsigned short*)alloc((size_t)BB * HH * 2);
  unsigned short* gh1 = (unsigned short*)alloc((size_t)BB * G3 * 2);  // also gi2
  float* o1t  = (float*)alloc((size_t)BB * OUTF * 4);
  float* auxp = (float*)alloc((size_t)TT * (BB * HH / 1024) * 4);
  unsigned short* gi2 = gh1;          // gh1 dead after gate1; stream order safe

  // gi1 slabs + gh2 placement. Mode A: 7 slabs, gh2(t) aliases dead slab
  // [t-1] (gate1(t-1) precedes gh_dual(t); t=0 needs no gh2 — bias path).
  // Mode B: dedicated gh2 + as many slabs as fit (fallback recompute).
  const size_t slabB = (size_t)BB * G3 * 2;
  const size_t slabE = (size_t)BB * G3;          // elements
  unsigned short* gh2 = nullptr;
  unsigned short* gi1s;
  int Th;
  bool modeA;
  if (ws_size - off >= 7 * slabB + 4096) {
    modeA = true;
    Th = TT;
    gi1s = (unsigned short*)alloc(7 * slabB);
  } else {
    modeA = false;
    gh2 = (unsigned short*)alloc(slabB);
    Th = (int)((ws_size > off ? (ws_size - off) : 0) / (slabB + 256));
    if (Th < 1) Th = 1;
    if (Th > TT) Th = TT;
    gi1s = (unsigned short*)alloc((size_t)Th * slabB);
  }

  float* aux = (float*)d_out + (size_t)BB * TT * OUTF;

  auto cvt = [&](const float* src, unsigned short* dst, size_t n) {
    int n4 = (int)(n / 4);
    cvt_f32_to_bf16_x4<<<dim3((n4 + 255) / 256), dim3(256), 0, stream>>>(src, dst, n4);
  };
  cvt_x_transpose<<<dim3(BB * TT * INF / 1024), dim3(256), 0, stream>>>(x, xbT);
  cvt(Wih1, wih1b, (size_t)G3 * INF);
  cvt(Whh1, whh1b, (size_t)G3 * HH);
  cvt(Wih2, wih2b, (size_t)G3 * HH);
  cvt(Whh2, whh2b, (size_t)G3 * HH);
  cvt(Wo1,  wo1b,  (size_t)OUTF * HH);
  cvt(Wo2,  wo2b,  (size_t)OUTF * HH);

  hipMemsetAsync(h1b, 0, (size_t)BB * HH * 2, stream);
  hipMemsetAsync(h2b, 0, (size_t)BB * HH * 2, stream);

  const dim3 blk(256);
  const int gateGrid = BB * HH / 1024;   // 4096

  // hoisted gi1 for steps [0, Th): one big GEMM, M = Th*4096
  k_gi1<<<dim3(Th * 768), blk, 0, stream>>>(xbT, wih1b, bih1, gi1s, Th * 32);

  for (int t = 0; t < TT; ++t) {
    const unsigned short* gi1_t;
    if (t < Th) {
      gi1_t = gi1s + (size_t)t * slabE;
    } else {
      // mode B only: recompute into slab 0 (hoisted content consumed at t=0)
      k_gi1<<<dim3(768), blk, 0, stream>>>(xbT + (size_t)t * BB * INF,
                                           wih1b, bih1, gi1s, 32);
      gi1_t = gi1s;
    }
    if (t == 0) {
      // h == 0: gates read the f32 bias directly (gh == bhh exactly)
      k_gate<true><<<dim3(gateGrid), blk, 0, stream>>>(gi1_t, (long)G3,
                                                       nullptr, bhh1, h1b, nullptr);
      k_gi2_o1<<<dim3(896), blk, 0, stream>>>(h1b, wih2b, bih2, gi2, wo1b, bo1, o1t);
      k_gate<true><<<dim3(gateGrid), blk, 0, stream>>>(gi2, (long)G3,
                                                       nullptr, bhh2, h2b,
                                                       auxp + (size_t)t * gateGrid);
    } else {
      unsigned short* gh2_t = modeA ? gi1s + (size_t)(t - 1) * slabE : gh2;
      k_gh_dual<<<dim3(1536), blk, 0, stream>>>(h1b, h2b, whh1b, whh2b, bhh1, bhh2,
                                                gh1, gh2_t);
      k_gate<false><<<dim3(gateGrid), blk, 0, stream>>>(gi1_t, (long)G3,
                                                        gh1, nullptr, h1b, nullptr);
      k_gi2_o1<<<dim3(896), blk, 0, stream>>>(h1b, wih2b, bih2, gi2, wo1b, bo1, o1t);
      k_gate<false><<<dim3(gateGrid), blk, 0, stream>>>(gi2, (long)G3,
                                                        gh2_t, nullptr, h2b,
                                                        auxp + (size_t)t * gateGrid);
    }
    k_o2_out<<<dim3(512), blk, 0, stream>>>(h2b, wo2b, bo2, o1t,
                                            (float*)d_out + (size_t)t * OUTF);
  }
  aux_reduce<<<dim3(1), blk, 0, stream>>>(auxp, TT * gateGrid, aux,
                                          1.f / ((float)BB * (float)HH));
}

// Round 17
// 1281.577 us; speedup vs baseline: 1.3017x; 1.0429x over previous
//
#include <hip/hip_runtime.h>
#include <cstdint>

#define BB   4096
#define TT   7
#define INF  512
#define HH   1024
#define OUTF 512
#define G3   3072   // 3*H

typedef short bf16x8 __attribute__((ext_vector_type(8)));
typedef float f32x4  __attribute__((ext_vector_type(4)));

static __device__ __forceinline__ unsigned short f2bf(float f) {
  unsigned u = __float_as_uint(f);
  unsigned r = ((u >> 16) & 1u) + 0x7FFFu;   // RNE
  return (unsigned short)((u + r) >> 16);
}
static __device__ __forceinline__ float bf2f(unsigned short s) {
  return __uint_as_float(((unsigned)s) << 16);
}

#define GLDS16(gp, lp)                                                        \
  __builtin_amdgcn_global_load_lds(                                           \
      (const __attribute__((address_space(1))) void*)(gp),                    \
      (__attribute__((address_space(3))) void*)(lp), 16, 0, 0)

__device__ __forceinline__ int xcd_swz(int bid, int nwg) {
  return (bid & 7) * (nwg >> 3) + (bid >> 3);   // bijective: nwg % 8 == 0
}

// x [B][T][INF] f32  ->  xbT [T][B][INF] bf16 (both sides coalesced in INF)
__global__ __launch_bounds__(256)
void cvt_x_transpose(const float* __restrict__ in, unsigned short* __restrict__ out) {
  const int i4 = blockIdx.x * 256 + threadIdx.x;   // over B*T*INF/4
  const long e = (long)i4 << 2;
  const int i  = (int)(e & (INF - 1));
  const long bt = e >> 9;                          // b*T + t
  const int t = (int)(bt % TT), b = (int)(bt / TT);
  const float4 v = *(const float4*)(in + e);
  ushort4 o;
  o.x = f2bf(v.x); o.y = f2bf(v.y); o.z = f2bf(v.z); o.w = f2bf(v.w);
  *(ushort4*)(out + ((size_t)t * BB + b) * INF + i) = o;
}

// all 6 weight conversions in one dispatch (segment-decoded, f32x4 units)
__global__ __launch_bounds__(256)
void k_cvt_w_all(const float* __restrict__ w1, const float* __restrict__ w2,
                 const float* __restrict__ w3, const float* __restrict__ w4,
                 const float* __restrict__ w5, const float* __restrict__ w6,
                 unsigned short* __restrict__ d1, unsigned short* __restrict__ d2,
                 unsigned short* __restrict__ d3, unsigned short* __restrict__ d4,
                 unsigned short* __restrict__ d5, unsigned short* __restrict__ d6)
{
  const int i = blockIdx.x * 256 + threadIdx.x;    // total 3,014,656 x4-units
  const float* s; unsigned short* d; int j;
  if (i < 393216)       { s = w1; d = d1; j = i; }
  else if (i < 1179648) { s = w2; d = d2; j = i - 393216; }
  else if (i < 1966080) { s = w3; d = d3; j = i - 1179648; }
  else if (i < 2752512) { s = w4; d = d4; j = i - 1966080; }
  else if (i < 2883584) { s = w5; d = d5; j = i - 2752512; }
  else                  { s = w6; d = d6; j = i - 2883584; }
  const float4 v = ((const float4*)s)[j];
  ushort4 o;
  o.x = f2bf(v.x); o.y = f2bf(v.y); o.z = f2bf(v.z); o.w = f2bf(v.w);
  ((ushort4*)d)[j] = o;
}

// ---------------------------------------------------------------------------
// r6-verified GEMM core: C = A @ W^T + bias. bf16 in, f32 acc. BK=64,
// double-buffered, chunk-XOR swizzle (0 conflicts). STAGE(next) before
// compute; plain __syncthreads schedule.
// mode: 0 f32; 1 bf16 tanh; 2 f32 tanh + bf16 add[]; 3 bf16.
// NOTE: exactly ONE gemm_core call per kernel (single __shared__ instance).
// ---------------------------------------------------------------------------
template<int BM, int BN, int WM, int WN, int GN>
__device__ __forceinline__ void gemm_core(
    const unsigned short* __restrict__ A, long lda, long bm,
    const unsigned short* __restrict__ Wp, long ldw, int K,
    const float* __restrict__ biasp,
    void* __restrict__ Cp, long ldc,
    const unsigned short* __restrict__ addp, long ldadd, int mode)
{
  constexpr int ABUF = BM * 64;
  constexpr int WBUF = BN * 64;
  constexpr int AR = (BM * 8) / 256;
  constexpr int WR = (BN * 8) / 256;
  __shared__ __attribute__((aligned(16))) unsigned short sm[2 * (ABUF + WBUF)];
  unsigned short* As = sm;
  unsigned short* Ws = sm + 2 * ABUF;
  __attribute__((address_space(3))) unsigned short* lAs =
      (__attribute__((address_space(3))) unsigned short*)As;
  __attribute__((address_space(3))) unsigned short* lWs =
      (__attribute__((address_space(3))) unsigned short*)Ws;

  const int tid  = threadIdx.x;
  const int lane = tid & 63;
  const int wid  = tid >> 6;
  const int wr = (wid / GN) * (WM * 16);
  const int wc = (wid % GN) * (WN * 16);
  const int fr = lane & 15;
  const int q2 = lane >> 4;

  const unsigned short* gpa[AR];
  const unsigned short* gpw[WR];
  int lofa[AR], lofw[WR];
#pragma unroll
  for (int r = 0; r < AR; ++r) {
    const int id = r * 256 + tid;
    const int row = id >> 3, cc = id & 7;
    gpa[r] = A + (bm + row) * lda + (cc ^ (row & 7)) * 8;
    lofa[r] = id * 8;
  }
#pragma unroll
  for (int r = 0; r < WR; ++r) {
    const int id = r * 256 + tid;
    const int row = id >> 3, cc = id & 7;
    gpw[r] = Wp + (long)row * ldw + (cc ^ (row & 7)) * 8;
    lofw[r] = id * 8;
  }

#define STAGE(buf, kt) do {                                                   \
    _Pragma("unroll")                                                         \
    for (int r = 0; r < AR; ++r) GLDS16(gpa[r] + (kt), lAs + (buf) * ABUF + lofa[r]); \
    _Pragma("unroll")                                                         \
    for (int r = 0; r < WR; ++r) GLDS16(gpw[r] + (kt), lWs + (buf) * WBUF + lofw[r]); \
  } while (0)

  f32x4 acc[WM][WN] = {};
  STAGE(0, 0);
  __syncthreads();
  const int NK = K >> 6;
  for (int it = 0; it < NK; ++it) {
    const int cur = it & 1;
    if (it + 1 < NK) STAGE(cur ^ 1, (it + 1) << 6);
#pragma unroll
    for (int ks = 0; ks < 2; ++ks) {
      bf16x8 af[WM], wf[WN];
#pragma unroll
      for (int i = 0; i < WM; ++i) {
        const int row = wr + i * 16 + fr;
        const int ch  = (ks * 4 + q2) ^ (row & 7);
        af[i] = *(const bf16x8*)&As[cur * ABUF + row * 64 + ch * 8];
      }
#pragma unroll
      for (int i = 0; i < WN; ++i) {
        const int row = wc + i * 16 + fr;
        const int ch  = (ks * 4 + q2) ^ (row & 7);
        wf[i] = *(const bf16x8*)&Ws[cur * WBUF + row * 64 + ch * 8];
      }
#pragma unroll
      for (int mi = 0; mi < WM; ++mi)
#pragma unroll
        for (int ni = 0; ni < WN; ++ni)
          acc[mi][ni] = __builtin_amdgcn_mfma_f32_16x16x32_bf16(af[mi], wf[ni], acc[mi][ni], 0, 0, 0);
    }
    __syncthreads();
  }
#undef STAGE

  const int q = lane >> 4;
#pragma unroll
  for (int ni = 0; ni < WN; ++ni) {
    const int col = wc + ni * 16 + fr;
    const float bv = biasp[col];
#pragma unroll
    for (int mi = 0; mi < WM; ++mi) {
      const long row = bm + wr + mi * 16 + q * 4;
#pragma unroll
      for (int j = 0; j < 4; ++j) {
        const float v = acc[mi][ni][j] + bv;
        if (mode == 0)      ((float*)Cp)[(row + j) * ldc + col] = v;
        else if (mode == 1) ((unsigned short*)Cp)[(row + j) * ldc + col] = f2bf(tanhf(v));
        else if (mode == 2) ((float*)Cp)[(row + j) * ldc + col] =
                                tanhf(v) + bf2f(addp[(row + j) * ldadd + col]);
        else                ((unsigned short*)Cp)[(row + j) * ldc + col] = f2bf(v);
      }
    }
  }
}

// gi1 (bf16 out, bias incl.). Hoisted: A = xbT (M = Th*4096), gx = Th*32.
// Per-step fallback (mode B): A = xbT + t*BB*INF, gx = 32.
__global__ __launch_bounds__(256)
void k_gi1(const unsigned short* __restrict__ A,
           const unsigned short* __restrict__ W, const float* __restrict__ bias,
           unsigned short* __restrict__ C, int gx)
{
  const int wg = xcd_swz(blockIdx.x, gridDim.x);
  const int bx = wg % gx, by = wg / gx;
  gemm_core<128,128,4,4,2>(A, INF, (long)bx * 128, W + (long)by * 128 * INF,
                           INF, INF, bias + by * 128, C + by * 128, G3, nullptr, 0, 3);
}

// gh1 = h1 @ Whh1^T and gh2 = h2 @ Whh2^T in one 1536-block dispatch (bf16 out)
__global__ __launch_bounds__(256)
void k_gh_dual(const unsigned short* __restrict__ h1b, const unsigned short* __restrict__ h2b,
               const unsigned short* __restrict__ W1, const unsigned short* __restrict__ W2,
               const float* __restrict__ b1, const float* __restrict__ b2,
               unsigned short* __restrict__ gh1, unsigned short* __restrict__ gh2)
{
  const int wg = xcd_swz(blockIdx.x, gridDim.x);   // 1536
  const int bx = wg % 32;
  const int by = (wg / 32) % 24;
  const int z  = wg / (32 * 24);
  const unsigned short* Aa = z ? h2b : h1b;
  const unsigned short* Ww = (z ? W2 : W1) + (long)by * 128 * HH;
  const float* bias = (z ? b2 : b1) + by * 128;
  unsigned short* C = (z ? gh2 : gh1) + by * 128;
  gemm_core<128,128,4,4,2>(Aa, HH, (long)bx * 128, Ww, HH, HH, bias, C, G3, nullptr, 0, 3);
}

// gi2 = h1 @ Wih2^T (bf16) and o1t = bf16 tanh(h1 @ Wo1^T + bo1), one call site
__global__ __launch_bounds__(256)
void k_gi2_o1(const unsigned short* __restrict__ h1b,
              const unsigned short* __restrict__ Wih2, const float* __restrict__ bih2,
              unsigned short* __restrict__ gi2,
              const unsigned short* __restrict__ Wo1, const float* __restrict__ bo1,
              unsigned short* __restrict__ o1t)
{
  const int wg = xcd_swz(blockIdx.x, gridDim.x);   // 896
  const int bx = wg % 32;
  const int by = wg / 32;
  const bool g = (by < 24);
  const int bo = by - 24;
  const unsigned short* Ww = g ? (Wih2 + (long)by * 128 * HH) : (Wo1 + (long)bo * 128 * HH);
  const float* bias        = g ? (bih2 + by * 128)            : (bo1 + bo * 128);
  void* C                  = g ? (void*)(gi2 + by * 128)      : (void*)(o1t + bo * 128);
  const long ldc           = g ? (long)G3 : (long)OUTF;
  gemm_core<128,128,4,4,2>(h1b, HH, (long)bx * 128, Ww, HH, HH, bias, C, ldc,
                           nullptr, 0, g ? 3 : 1);
}

// out[b,t,:] = tanh(h2 @ Wo2^T + bo2) + bf2f(o1t)   (64x64 tiles, 512 blocks)
__global__ __launch_bounds__(256)
void k_o2_out(const unsigned short* __restrict__ h2b,
              const unsigned short* __restrict__ Wo2, const float* __restrict__ bo2,
              const unsigned short* __restrict__ o1t, float* __restrict__ outp)
{
  const int wg = xcd_swz(blockIdx.x, gridDim.x);   // 512
  const int bx = wg % 64;
  const int by = wg / 64;
  gemm_core<64,64,2,2,2>(h2b, HH, (long)bx * 64, Wo2 + (long)by * 64 * HH, HH, HH,
                         bo2 + by * 64, outp + by * 64, (long)TT * OUTF,
                         o1t + by * 64, OUTF, 2);
}

// GRU gate: h = (1-z)*n + z*h_old. gi bf16; gh bf16 OR (BIAS: t=0) f32 bias
// broadcast with h_old == 0 (gh = 0 @ Whh^T + bhh = bhh exactly).
template<bool BIAS>
__global__ __launch_bounds__(256)
void k_gate(const unsigned short* __restrict__ gi, long gistride,
            const unsigned short* __restrict__ gh, const float* __restrict__ ghb,
            unsigned short* __restrict__ hb,
            float* __restrict__ auxp)
{
  const int i4 = blockIdx.x * 256 + threadIdx.x;
  const int e  = i4 << 2;
  const int b = e >> 10;                  // H = 1024
  const int c = e & 1023;
  const unsigned short* g = gi + (long)b * gistride + c;
  const ushort4 a0 = *(const ushort4*)(g);
  const ushort4 a1 = *(const ushort4*)(g + HH);
  const ushort4 a2 = *(const ushort4*)(g + 2 * HH);
  const f32x4 ir  = f32x4{bf2f(a0.x), bf2f(a0.y), bf2f(a0.z), bf2f(a0.w)};
  const f32x4 iz  = f32x4{bf2f(a1.x), bf2f(a1.y), bf2f(a1.z), bf2f(a1.w)};
  const f32x4 inn = f32x4{bf2f(a2.x), bf2f(a2.y), bf2f(a2.z), bf2f(a2.w)};
  f32x4 hr, hz, hn, h;
  if (BIAS) {
    hr = *(const f32x4*)(ghb + c);
    hz = *(const f32x4*)(ghb + HH + c);
    hn = *(const f32x4*)(ghb + 2 * HH + c);
    h  = f32x4{0.f, 0.f, 0.f, 0.f};
  } else {
    const unsigned short* gg = gh + (long)b * G3 + c;
    const ushort4 b0 = *(const ushort4*)(gg);
    const ushort4 b1 = *(const ushort4*)(gg + HH);
    const ushort4 b2 = *(const ushort4*)(gg + 2 * HH);
    hr = f32x4{bf2f(b0.x), bf2f(b0.y), bf2f(b0.z), bf2f(b0.w)};
    hz = f32x4{bf2f(b1.x), bf2f(b1.y), bf2f(b1.z), bf2f(b1.w)};
    hn = f32x4{bf2f(b2.x), bf2f(b2.y), bf2f(b2.z), bf2f(b2.w)};
    const ushort4 ho = *(const ushort4*)(hb + e);
    h = f32x4{bf2f(ho.x), bf2f(ho.y), bf2f(ho.z), bf2f(ho.w)};
  }
  f32x4 hnew;
  float vsum = 0.f;
#pragma unroll
  for (int j = 0; j < 4; ++j) {
    const float r = 1.f / (1.f + __expf(-(ir[j] + hr[j])));
    const float z = 1.f / (1.f + __expf(-(iz[j] + hz[j])));
    const float n = tanhf(inn[j] + r * hn[j]);
    hnew[j] = (1.f - z) * n + z * h[j];
    vsum += hnew[j] * hnew[j];
  }
  ushort4 o;
  o.x = f2bf(hnew[0]); o.y = f2bf(hnew[1]); o.z = f2bf(hnew[2]); o.w = f2bf(hnew[3]);
  *(ushort4*)(hb + e) = o;
  if (auxp != nullptr) {
#pragma unroll
    for (int off = 32; off > 0; off >>= 1) vsum += __shfl_down(vsum, off);
    __shared__ float wsum[4];
    if ((threadIdx.x & 63) == 0) wsum[threadIdx.x >> 6] = vsum;
    __syncthreads();
    if (threadIdx.x == 0) auxp[blockIdx.x] = wsum[0] + wsum[1] + wsum[2] + wsum[3];
  }
}

__global__ __launch_bounds__(256)
void aux_reduce(const float* __restrict__ p, int n, float* __restrict__ out, float scale) {
  float s = 0.f;
  for (int i = threadIdx.x; i < n; i += 256) s += p[i];
#pragma unroll
  for (int off = 32; off > 0; off >>= 1) s += __shfl_down(s, off);
  __shared__ float wsum[4];
  if ((threadIdx.x & 63) == 0) wsum[threadIdx.x >> 6] = s;
  __syncthreads();
  if (threadIdx.x == 0) out[0] = (wsum[0] + wsum[1] + wsum[2] + wsum[3]) * scale;
}

extern "C" void kernel_launch(void* const* d_in, const int* in_sizes, int n_in,
                              void* d_out, int out_size, void* d_ws, size_t ws_size,
                              hipStream_t stream) {
  const float* x    = (const float*)d_in[0];
  const float* Wih1 = (const float*)d_in[1];
  const float* Whh1 = (const float*)d_in[2];
  const float* bih1 = (const float*)d_in[3];
  const float* bhh1 = (const float*)d_in[4];
  const float* Wih2 = (const float*)d_in[5];
  const float* Whh2 = (const float*)d_in[6];
  const float* bih2 = (const float*)d_in[7];
  const float* bhh2 = (const float*)d_in[8];
  const float* Wo1  = (const float*)d_in[9];
  const float* bo1  = (const float*)d_in[10];
  const float* Wo2  = (const float*)d_in[11];
  const float* bo2  = (const float*)d_in[12];

  char* ws = (char*)d_ws;
  size_t off = 0;
  auto alloc = [&](size_t bytes) {
    char* p = ws + off;
    off = (off + bytes + 255) & ~(size_t)255;
    return p;
  };

  unsigned short* xbT   = (unsigned short*)alloc((size_t)BB * TT * INF * 2);  // [T][B][INF]
  unsigned short* wih1b = (unsigned short*)alloc((size_t)G3 * INF * 2);
  unsigned short* whh1b = (unsigned short*)alloc((size_t)G3 * HH * 2);
  unsigned short* wih2b = (unsigned short*)alloc((size_t)G3 * HH * 2);
  unsigned short* whh2b = (unsigned short*)alloc((size_t)G3 * HH * 2);
  unsigned short* wo1b  = (unsigned short*)alloc((size_t)OUTF * HH * 2);
  unsigned short* wo2b  = (unsigned short*)alloc((size_t)OUTF * HH * 2);
  unsigned short* h1b = (unsigned short*)alloc((size_t)BB * HH * 2);
  unsigned short* h2b = (unsigned short*)alloc((size_t)BB * HH * 2);
  unsigned short* o1t = (unsigned short*)alloc((size_t)BB * OUTF * 2);   // bf16 now
  float* auxp = (float*)alloc((size_t)TT * (BB * HH / 1024) * 4);

  // gi1 slabs + gh placement.
  // Scheme X (full hoist): 7 slabs; gh1/gi2 alias the dead xbT region
  // (28.7 MB >= 25.2 MB; xbT fully consumed by the hoist GEMM); gh2(t)
  // aliases dead slab[t-1] (consumed by gate1(t-1)); t=0 uses bias gates.
  // Mode B (fallback): dedicated gh1/gh2, Th slabs, per-step recompute.
  const size_t slabB = (size_t)BB * G3 * 2;
  const size_t slabE = (size_t)BB * G3;          // elements
  unsigned short* gh1;
  unsigned short* gh2ded = nullptr;
  unsigned short* gi1s;
  int Th;
  bool schemeX;
  if (ws_size >= off + 7 * slabB) {
    schemeX = true;
    Th = TT;
    gi1s = (unsigned short*)alloc(7 * slabB);
    gh1 = xbT;                               // dead after hoist GEMM
  } else {
    schemeX = false;
    gh1 = (unsigned short*)alloc(slabB);
    gh2ded = (unsigned short*)alloc(slabB);
    Th = (int)((ws_size > off ? (ws_size - off) : 0) / (slabB + 256));
    if (Th < 1) Th = 1;
    if (Th > TT) Th = TT;
    gi1s = (unsigned short*)alloc((size_t)Th * slabB);
  }
  unsigned short* gi2 = gh1;                 // gh1 dead after gate1; sequential

  float* aux = (float*)d_out + (size_t)BB * TT * OUTF;

  cvt_x_transpose<<<dim3(BB * TT * INF / 1024), dim3(256), 0, stream>>>(x, xbT);
  k_cvt_w_all<<<dim3(3014656 / 256), dim3(256), 0, stream>>>(
      Wih1, Whh1, Wih2, Whh2, Wo1, Wo2,
      wih1b, whh1b, wih2b, whh2b, wo1b, wo2b);

  hipMemsetAsync(h1b, 0, (size_t)BB * HH * 2, stream);
  hipMemsetAsync(h2b, 0, (size_t)BB * HH * 2, stream);

  const dim3 blk(256);
  const int gateGrid = BB * HH / 1024;   // 4096

  // hoisted gi1 for steps [0, Th): one big GEMM, M = Th*4096
  k_gi1<<<dim3(Th * 768), blk, 0, stream>>>(xbT, wih1b, bih1, gi1s, Th * 32);

  for (int t = 0; t < TT; ++t) {
    const unsigned short* gi1_t;
    if (t < Th) {
      gi1_t = gi1s + (size_t)t * slabE;
    } else {
      // mode B only: recompute into slab 0 (hoisted content consumed at t=0)
      k_gi1<<<dim3(768), blk, 0, stream>>>(xbT + (size_t)t * BB * INF,
                                           wih1b, bih1, gi1s, 32);
      gi1_t = gi1s;
    }
    if (t == 0) {
      // h == 0: gates read the f32 bias directly (gh == bhh exactly)
      k_gate<true><<<dim3(gateGrid), blk, 0, stream>>>(gi1_t, (long)G3,
                                                       nullptr, bhh1, h1b, nullptr);
      k_gi2_o1<<<dim3(896), blk, 0, stream>>>(h1b, wih2b, bih2, gi2, wo1b, bo1, o1t);
      k_gate<true><<<dim3(gateGrid), blk, 0, stream>>>(gi2, (long)G3,
                                                       nullptr, bhh2, h2b,
                                                       auxp + (size_t)t * gateGrid);
    } else {
      unsigned short* gh2_t = schemeX ? gi1s + (size_t)(t - 1) * slabE : gh2ded;
      k_gh_dual<<<dim3(1536), blk, 0, stream>>>(h1b, h2b, whh1b, whh2b, bhh1, bhh2,
                                                gh1, gh2_t);
      k_gate<false><<<dim3(gateGrid), blk, 0, stream>>>(gi1_t, (long)G3,
                                                        gh1, nullptr, h1b, nullptr);
      k_gi2_o1<<<dim3(896), blk, 0, stream>>>(h1b, wih2b, bih2, gi2, wo1b, bo1, o1t);
      k_gate<false><<<dim3(gateGrid), blk, 0, stream>>>(gi2, (long)G3,
                                                        gh2_t, nullptr, h2b,
                                                        auxp + (size_t)t * gateGrid);
    }
    k_o2_out<<<dim3(512), blk, 0, stream>>>(h2b, wo2b, bo2, o1t,
                                            (float*)d_out + (size_t)t * OUTF);
  }
  aux_reduce<<<dim3(1), blk, 0, stream>>>(auxp, TT * gateGrid, aux,
                                          1.f / ((float)BB * (float)HH));
}

// Round 18
// 1261.684 us; speedup vs baseline: 1.3223x; 1.0158x over previous
//
#include <hip/hip_runtime.h>
#include <cstdint>

#define BB   4096
#define TT   7
#define INF  512
#define HH   1024
#define OUTF 512
#define G3   3072   // 3*H

typedef short bf16x8 __attribute__((ext_vector_type(8)));
typedef float f32x4  __attribute__((ext_vector_type(4)));

static __device__ __forceinline__ unsigned short f2bf(float f) {
  unsigned u = __float_as_uint(f);
  unsigned r = ((u >> 16) & 1u) + 0x7FFFu;   // RNE
  return (unsigned short)((u + r) >> 16);
}
static __device__ __forceinline__ float bf2f(unsigned short s) {
  return __uint_as_float(((unsigned)s) << 16);
}

#define GLDS16(gp, lp)                                                        \
  __builtin_amdgcn_global_load_lds(                                           \
      (const __attribute__((address_space(1))) void*)(gp),                    \
      (__attribute__((address_space(3))) void*)(lp), 16, 0, 0)

__device__ __forceinline__ int xcd_swz(int bid, int nwg) {
  return (bid & 7) * (nwg >> 3) + (bid >> 3);   // bijective: nwg % 8 == 0
}

// x [B][T][INF] f32  ->  xbT [T][B][INF] bf16 (both sides coalesced in INF)
__global__ __launch_bounds__(256)
void cvt_x_transpose(const float* __restrict__ in, unsigned short* __restrict__ out) {
  const int i4 = blockIdx.x * 256 + threadIdx.x;   // over B*T*INF/4
  const long e = (long)i4 << 2;
  const int i  = (int)(e & (INF - 1));
  const long bt = e >> 9;                          // b*T + t
  const int t = (int)(bt % TT), b = (int)(bt / TT);
  const float4 v = *(const float4*)(in + e);
  ushort4 o;
  o.x = f2bf(v.x); o.y = f2bf(v.y); o.z = f2bf(v.z); o.w = f2bf(v.w);
  *(ushort4*)(out + ((size_t)t * BB + b) * INF + i) = o;
}

// all 6 weight conversions in one dispatch (segment-decoded, f32x4 units)
__global__ __launch_bounds__(256)
void k_cvt_w_all(const float* __restrict__ w1, const float* __restrict__ w2,
                 const float* __restrict__ w3, const float* __restrict__ w4,
                 const float* __restrict__ w5, const float* __restrict__ w6,
                 unsigned short* __restrict__ d1, unsigned short* __restrict__ d2,
                 unsigned short* __restrict__ d3, unsigned short* __restrict__ d4,
                 unsigned short* __restrict__ d5, unsigned short* __restrict__ d6)
{
  const int i = blockIdx.x * 256 + threadIdx.x;    // total 3,014,656 x4-units
  const float* s; unsigned short* d; int j;
  if (i < 393216)       { s = w1; d = d1; j = i; }
  else if (i < 1179648) { s = w2; d = d2; j = i - 393216; }
  else if (i < 1966080) { s = w3; d = d3; j = i - 1179648; }
  else if (i < 2752512) { s = w4; d = d4; j = i - 1966080; }
  else if (i < 2883584) { s = w5; d = d5; j = i - 2752512; }
  else                  { s = w6; d = d6; j = i - 2883584; }
  const float4 v = ((const float4*)s)[j];
  ushort4 o;
  o.x = f2bf(v.x); o.y = f2bf(v.y); o.z = f2bf(v.z); o.w = f2bf(v.w);
  ((ushort4*)d)[j] = o;
}

// ---------------------------------------------------------------------------
// r6-verified GEMM core: C = A @ W^T + bias. bf16 in, f32 acc. BK=64,
// double-buffered, chunk-XOR swizzle (0 conflicts). STAGE(next) before
// compute; plain __syncthreads schedule.
// mode: 0 f32; 1 bf16 tanh; 2 f32 tanh + bf16 add[]; 3 bf16.
// NOTE: exactly ONE gemm_core call per kernel (single __shared__ instance).
// ---------------------------------------------------------------------------
template<int BM, int BN, int WM, int WN, int GN>
__device__ __forceinline__ void gemm_core(
    const unsigned short* __restrict__ A, long lda, long bm,
    const unsigned short* __restrict__ Wp, long ldw, int K,
    const float* __restrict__ biasp,
    void* __restrict__ Cp, long ldc,
    const unsigned short* __restrict__ addp, long ldadd, int mode)
{
  constexpr int ABUF = BM * 64;
  constexpr int WBUF = BN * 64;
  constexpr int AR = (BM * 8) / 256;
  constexpr int WR = (BN * 8) / 256;
  __shared__ __attribute__((aligned(16))) unsigned short sm[2 * (ABUF + WBUF)];
  unsigned short* As = sm;
  unsigned short* Ws = sm + 2 * ABUF;
  __attribute__((address_space(3))) unsigned short* lAs =
      (__attribute__((address_space(3))) unsigned short*)As;
  __attribute__((address_space(3))) unsigned short* lWs =
      (__attribute__((address_space(3))) unsigned short*)Ws;

  const int tid  = threadIdx.x;
  const int lane = tid & 63;
  const int wid  = tid >> 6;
  const int wr = (wid / GN) * (WM * 16);
  const int wc = (wid % GN) * (WN * 16);
  const int fr = lane & 15;
  const int q2 = lane >> 4;

  const unsigned short* gpa[AR];
  const unsigned short* gpw[WR];
  int lofa[AR], lofw[WR];
#pragma unroll
  for (int r = 0; r < AR; ++r) {
    const int id = r * 256 + tid;
    const int row = id >> 3, cc = id & 7;
    gpa[r] = A + (bm + row) * lda + (cc ^ (row & 7)) * 8;
    lofa[r] = id * 8;
  }
#pragma unroll
  for (int r = 0; r < WR; ++r) {
    const int id = r * 256 + tid;
    const int row = id >> 3, cc = id & 7;
    gpw[r] = Wp + (long)row * ldw + (cc ^ (row & 7)) * 8;
    lofw[r] = id * 8;
  }

#define STAGE(buf, kt) do {                                                   \
    _Pragma("unroll")                                                         \
    for (int r = 0; r < AR; ++r) GLDS16(gpa[r] + (kt), lAs + (buf) * ABUF + lofa[r]); \
    _Pragma("unroll")                                                         \
    for (int r = 0; r < WR; ++r) GLDS16(gpw[r] + (kt), lWs + (buf) * WBUF + lofw[r]); \
  } while (0)

  f32x4 acc[WM][WN] = {};
  STAGE(0, 0);
  __syncthreads();
  const int NK = K >> 6;
  for (int it = 0; it < NK; ++it) {
    const int cur = it & 1;
    if (it + 1 < NK) STAGE(cur ^ 1, (it + 1) << 6);
#pragma unroll
    for (int ks = 0; ks < 2; ++ks) {
      bf16x8 af[WM], wf[WN];
#pragma unroll
      for (int i = 0; i < WM; ++i) {
        const int row = wr + i * 16 + fr;
        const int ch  = (ks * 4 + q2) ^ (row & 7);
        af[i] = *(const bf16x8*)&As[cur * ABUF + row * 64 + ch * 8];
      }
#pragma unroll
      for (int i = 0; i < WN; ++i) {
        const int row = wc + i * 16 + fr;
        const int ch  = (ks * 4 + q2) ^ (row & 7);
        wf[i] = *(const bf16x8*)&Ws[cur * WBUF + row * 64 + ch * 8];
      }
#pragma unroll
      for (int mi = 0; mi < WM; ++mi)
#pragma unroll
        for (int ni = 0; ni < WN; ++ni)
          acc[mi][ni] = __builtin_amdgcn_mfma_f32_16x16x32_bf16(af[mi], wf[ni], acc[mi][ni], 0, 0, 0);
    }
    __syncthreads();
  }
#undef STAGE

  const int q = lane >> 4;
#pragma unroll
  for (int ni = 0; ni < WN; ++ni) {
    const int col = wc + ni * 16 + fr;
    const float bv = biasp[col];
#pragma unroll
    for (int mi = 0; mi < WM; ++mi) {
      const long row = bm + wr + mi * 16 + q * 4;
#pragma unroll
      for (int j = 0; j < 4; ++j) {
        const float v = acc[mi][ni][j] + bv;
        if (mode == 0)      ((float*)Cp)[(row + j) * ldc + col] = v;
        else if (mode == 1) ((unsigned short*)Cp)[(row + j) * ldc + col] = f2bf(tanhf(v));
        else if (mode == 2) ((float*)Cp)[(row + j) * ldc + col] =
                                tanhf(v) + bf2f(addp[(row + j) * ldadd + col]);
        else                ((unsigned short*)Cp)[(row + j) * ldc + col] = f2bf(v);
      }
    }
  }
}

// gi1 (bf16 out, bias incl.). by-FAST runtime decode (nby = 24): each XCD's
// contiguous swizzle chunk covers all 24 W-panels x few bx row-slabs -> x is
// read ~once per XCD (fixes the 8x x-overfetch: r17 FETCH 348 MB vs ~32
// ideal). Runtime divisor keeps VGPR at 112 (r14's compile-time /24 bloated
// to 132 and halved occupancy). Hoist: grid Th*768. Fallback: grid 768.
__global__ __launch_bounds__(256)
void k_gi1(const unsigned short* __restrict__ A,
           const unsigned short* __restrict__ W, const float* __restrict__ bias,
           unsigned short* __restrict__ C, int nby)
{
  const int wg = xcd_swz(blockIdx.x, gridDim.x);
  const int by = wg % nby, bx = wg / nby;
  gemm_core<128,128,4,4,2>(A, INF, (long)bx * 128, W + (long)by * 128 * INF,
                           INF, INF, bias + by * 128, C + by * 128, G3, nullptr, 0, 3);
}

// gh1 = h1 @ Whh1^T and gh2 = h2 @ Whh2^T in one 1536-block dispatch (bf16 out)
__global__ __launch_bounds__(256)
void k_gh_dual(const unsigned short* __restrict__ h1b, const unsigned short* __restrict__ h2b,
               const unsigned short* __restrict__ W1, const unsigned short* __restrict__ W2,
               const float* __restrict__ b1, const float* __restrict__ b2,
               unsigned short* __restrict__ gh1, unsigned short* __restrict__ gh2)
{
  const int wg = xcd_swz(blockIdx.x, gridDim.x);   // 1536
  const int bx = wg % 32;
  const int by = (wg / 32) % 24;
  const int z  = wg / (32 * 24);
  const unsigned short* Aa = z ? h2b : h1b;
  const unsigned short* Ww = (z ? W2 : W1) + (long)by * 128 * HH;
  const float* bias = (z ? b2 : b1) + by * 128;
  unsigned short* C = (z ? gh2 : gh1) + by * 128;
  gemm_core<128,128,4,4,2>(Aa, HH, (long)bx * 128, Ww, HH, HH, bias, C, G3, nullptr, 0, 3);
}

// gi2 = h1 @ Wih2^T (bf16) and o1t = bf16 tanh(h1 @ Wo1^T + bo1), one call site
__global__ __launch_bounds__(256)
void k_gi2_o1(const unsigned short* __restrict__ h1b,
              const unsigned short* __restrict__ Wih2, const float* __restrict__ bih2,
              unsigned short* __restrict__ gi2,
              const unsigned short* __restrict__ Wo1, const float* __restrict__ bo1,
              unsigned short* __restrict__ o1t)
{
  const int wg = xcd_swz(blockIdx.x, gridDim.x);   // 896
  const int bx = wg % 32;
  const int by = wg / 32;
  const bool g = (by < 24);
  const int bo = by - 24;
  const unsigned short* Ww = g ? (Wih2 + (long)by * 128 * HH) : (Wo1 + (long)bo * 128 * HH);
  const float* bias        = g ? (bih2 + by * 128)            : (bo1 + bo * 128);
  void* C                  = g ? (void*)(gi2 + by * 128)      : (void*)(o1t + bo * 128);
  const long ldc           = g ? (long)G3 : (long)OUTF;
  gemm_core<128,128,4,4,2>(h1b, HH, (long)bx * 128, Ww, HH, HH, bias, C, ldc,
                           nullptr, 0, g ? 3 : 1);
}

// out[b,t,:] = tanh(h2 @ Wo2^T + bo2) + bf2f(o1t)   (64x64 tiles, 512 blocks)
__global__ __launch_bounds__(256)
void k_o2_out(const unsigned short* __restrict__ h2b,
              const unsigned short* __restrict__ Wo2, const float* __restrict__ bo2,
              const unsigned short* __restrict__ o1t, float* __restrict__ outp)
{
  const int wg = xcd_swz(blockIdx.x, gridDim.x);   // 512
  const int bx = wg % 64;
  const int by = wg / 64;
  gemm_core<64,64,2,2,2>(h2b, HH, (long)bx * 64, Wo2 + (long)by * 64 * HH, HH, HH,
                         bo2 + by * 64, outp + by * 64, (long)TT * OUTF,
                         o1t + by * 64, OUTF, 2);
}

// GRU gate: h = (1-z)*n + z*h_old. gi bf16; gh bf16 OR (BIAS: t=0) f32 bias
// broadcast with h_old == 0 (gh = 0 @ Whh^T + bhh = bhh exactly).
template<bool BIAS>
__global__ __launch_bounds__(256)
void k_gate(const unsigned short* __restrict__ gi, long gistride,
            const unsigned short* __restrict__ gh, const float* __restrict__ ghb,
            unsigned short* __restrict__ hb,
            float* __restrict__ auxp)
{
  const int i4 = blockIdx.x * 256 + threadIdx.x;
  const int e  = i4 << 2;
  const int b = e >> 10;                  // H = 1024
  const int c = e & 1023;
  const unsigned short* g = gi + (long)b * gistride + c;
  const ushort4 a0 = *(const ushort4*)(g);
  const ushort4 a1 = *(const ushort4*)(g + HH);
  const ushort4 a2 = *(const ushort4*)(g + 2 * HH);
  const f32x4 ir  = f32x4{bf2f(a0.x), bf2f(a0.y), bf2f(a0.z), bf2f(a0.w)};
  const f32x4 iz  = f32x4{bf2f(a1.x), bf2f(a1.y), bf2f(a1.z), bf2f(a1.w)};
  const f32x4 inn = f32x4{bf2f(a2.x), bf2f(a2.y), bf2f(a2.z), bf2f(a2.w)};
  f32x4 hr, hz, hn, h;
  if (BIAS) {
    hr = *(const f32x4*)(ghb + c);
    hz = *(const f32x4*)(ghb + HH + c);
    hn = *(const f32x4*)(ghb + 2 * HH + c);
    h  = f32x4{0.f, 0.f, 0.f, 0.f};
  } else {
    const unsigned short* gg = gh + (long)b * G3 + c;
    const ushort4 b0 = *(const ushort4*)(gg);
    const ushort4 b1 = *(const ushort4*)(gg + HH);
    const ushort4 b2 = *(const ushort4*)(gg + 2 * HH);
    hr = f32x4{bf2f(b0.x), bf2f(b0.y), bf2f(b0.z), bf2f(b0.w)};
    hz = f32x4{bf2f(b1.x), bf2f(b1.y), bf2f(b1.z), bf2f(b1.w)};
    hn = f32x4{bf2f(b2.x), bf2f(b2.y), bf2f(b2.z), bf2f(b2.w)};
    const ushort4 ho = *(const ushort4*)(hb + e);
    h = f32x4{bf2f(ho.x), bf2f(ho.y), bf2f(ho.z), bf2f(ho.w)};
  }
  f32x4 hnew;
  float vsum = 0.f;
#pragma unroll
  for (int j = 0; j < 4; ++j) {
    const float r = 1.f / (1.f + __expf(-(ir[j] + hr[j])));
    const float z = 1.f / (1.f + __expf(-(iz[j] + hz[j])));
    const float n = tanhf(inn[j] + r * hn[j]);
    hnew[j] = (1.f - z) * n + z * h[j];
    vsum += hnew[j] * hnew[j];
  }
  ushort4 o;
  o.x = f2bf(hnew[0]); o.y = f2bf(hnew[1]); o.z = f2bf(hnew[2]); o.w = f2bf(hnew[3]);
  *(ushort4*)(hb + e) = o;
  if (auxp != nullptr) {
#pragma unroll
    for (int off = 32; off > 0; off >>= 1) vsum += __shfl_down(vsum, off);
    __shared__ float wsum[4];
    if ((threadIdx.x & 63) == 0) wsum[threadIdx.x >> 6] = vsum;
    __syncthreads();
    if (threadIdx.x == 0) auxp[blockIdx.x] = wsum[0] + wsum[1] + wsum[2] + wsum[3];
  }
}

__global__ __launch_bounds__(256)
void aux_reduce(const float* __restrict__ p, int n, float* __restrict__ out, float scale) {
  float s = 0.f;
  for (int i = threadIdx.x; i < n; i += 256) s += p[i];
#pragma unroll
  for (int off = 32; off > 0; off >>= 1) s += __shfl_down(s, off);
  __shared__ float wsum[4];
  if ((threadIdx.x & 63) == 0) wsum[threadIdx.x >> 6] = s;
  __syncthreads();
  if (threadIdx.x == 0) out[0] = (wsum[0] + wsum[1] + wsum[2] + wsum[3]) * scale;
}

extern "C" void kernel_launch(void* const* d_in, const int* in_sizes, int n_in,
                              void* d_out, int out_size, void* d_ws, size_t ws_size,
                              hipStream_t stream) {
  const float* x    = (const float*)d_in[0];
  const float* Wih1 = (const float*)d_in[1];
  const float* Whh1 = (const float*)d_in[2];
  const float* bih1 = (const float*)d_in[3];
  const float* bhh1 = (const float*)d_in[4];
  const float* Wih2 = (const float*)d_in[5];
  const float* Whh2 = (const float*)d_in[6];
  const float* bih2 = (const float*)d_in[7];
  const float* bhh2 = (const float*)d_in[8];
  const float* Wo1  = (const float*)d_in[9];
  const float* bo1  = (const float*)d_in[10];
  const float* Wo2  = (const float*)d_in[11];
  const float* bo2  = (const float*)d_in[12];

  char* ws = (char*)d_ws;
  size_t off = 0;
  auto alloc = [&](size_t bytes) {
    char* p = ws + off;
    off = (off + bytes + 255) & ~(size_t)255;
    return p;
  };

  unsigned short* xbT   = (unsigned short*)alloc((size_t)BB * TT * INF * 2);  // [T][B][INF]
  unsigned short* wih1b = (unsigned short*)alloc((size_t)G3 * INF * 2);
  unsigned short* whh1b = (unsigned short*)alloc((size_t)G3 * HH * 2);
  unsigned short* wih2b = (unsigned short*)alloc((size_t)G3 * HH * 2);
  unsigned short* whh2b = (unsigned short*)alloc((size_t)G3 * HH * 2);
  unsigned short* wo1b  = (unsigned short*)alloc((size_t)OUTF * HH * 2);
  unsigned short* wo2b  = (unsigned short*)alloc((size_t)OUTF * HH * 2);
  unsigned short* h1b = (unsigned short*)alloc((size_t)BB * HH * 2);
  unsigned short* h2b = (unsigned short*)alloc((size_t)BB * HH * 2);
  unsigned short* o1t = (unsigned short*)alloc((size_t)BB * OUTF * 2);   // bf16
  float* auxp = (float*)alloc((size_t)TT * (BB * HH / 1024) * 4);

  // gi1 slabs + gh placement.
  // Scheme X (full hoist): 7 slabs; gh1/gi2 alias the dead xbT region
  // (28.7 MB >= 25.2 MB; xbT fully consumed by the hoist GEMM); gh2(t)
  // aliases dead slab[t-1] (consumed by gate1(t-1)); t=0 uses bias gates.
  // Mode B (fallback): dedicated gh1/gh2, Th slabs, per-step recompute.
  const size_t slabB = (size_t)BB * G3 * 2;
  const size_t slabE = (size_t)BB * G3;          // elements
  unsigned short* gh1;
  unsigned short* gh2ded = nullptr;
  unsigned short* gi1s;
  int Th;
  bool schemeX;
  if (ws_size >= off + 7 * slabB) {
    schemeX = true;
    Th = TT;
    gi1s = (unsigned short*)alloc(7 * slabB);
    gh1 = xbT;                               // dead after hoist GEMM
  } else {
    schemeX = false;
    gh1 = (unsigned short*)alloc(slabB);
    gh2ded = (unsigned short*)alloc(slabB);
    Th = (int)((ws_size > off ? (ws_size - off) : 0) / (slabB + 256));
    if (Th < 1) Th = 1;
    if (Th > TT) Th = TT;
    gi1s = (unsigned short*)alloc((size_t)Th * slabB);
  }
  unsigned short* gi2 = gh1;                 // gh1 dead after gate1; sequential

  float* aux = (float*)d_out + (size_t)BB * TT * OUTF;

  cvt_x_transpose<<<dim3(BB * TT * INF / 1024), dim3(256), 0, stream>>>(x, xbT);
  k_cvt_w_all<<<dim3(3014656 / 256), dim3(256), 0, stream>>>(
      Wih1, Whh1, Wih2, Whh2, Wo1, Wo2,
      wih1b, whh1b, wih2b, whh2b, wo1b, wo2b);

  hipMemsetAsync(h1b, 0, (size_t)BB * HH * 2, stream);
  hipMemsetAsync(h2b, 0, (size_t)BB * HH * 2, stream);

  const dim3 blk(256);
  const int gateGrid = BB * HH / 1024;   // 4096

  // hoisted gi1 for steps [0, Th): one big GEMM, M = Th*4096
  k_gi1<<<dim3(Th * 768), blk, 0, stream>>>(xbT, wih1b, bih1, gi1s, 24);

  for (int t = 0; t < TT; ++t) {
    const unsigned short* gi1_t;
    if (t < Th) {
      gi1_t = gi1s + (size_t)t * slabE;
    } else {
      // mode B only: recompute into slab 0 (hoisted content consumed at t=0)
      k_gi1<<<dim3(768), blk, 0, stream>>>(xbT + (size_t)t * BB * INF,
                                           wih1b, bih1, gi1s, 24);
      gi1_t = gi1s;
    }
    if (t == 0) {
      // h == 0: gates read the f32 bias directly (gh == bhh exactly)
      k_gate<true><<<dim3(gateGrid), blk, 0, stream>>>(gi1_t, (long)G3,
                                                       nullptr, bhh1, h1b, nullptr);
      k_gi2_o1<<<dim3(896), blk, 0, stream>>>(h1b, wih2b, bih2, gi2, wo1b, bo1, o1t);
      k_gate<true><<<dim3(gateGrid), blk, 0, stream>>>(gi2, (long)G3,
                                                       nullptr, bhh2, h2b,
                                                       auxp + (size_t)t * gateGrid);
    } else {
      unsigned short* gh2_t = schemeX ? gi1s + (size_t)(t - 1) * slabE : gh2ded;
      k_gh_dual<<<dim3(1536), blk, 0, stream>>>(h1b, h2b, whh1b, whh2b, bhh1, bhh2,
                                                gh1, gh2_t);
      k_gate<false><<<dim3(gateGrid), blk, 0, stream>>>(gi1_t, (long)G3,
                                                        gh1, nullptr, h1b, nullptr);
      k_gi2_o1<<<dim3(896), blk, 0, stream>>>(h1b, wih2b, bih2, gi2, wo1b, bo1, o1t);
      k_gate<false><<<dim3(gateGrid), blk, 0, stream>>>(gi2, (long)G3,
                                                        gh2_t, nullptr, h2b,
                                                        auxp + (size_t)t * gateGrid);
    }
    k_o2_out<<<dim3(512), blk, 0, stream>>>(h2b, wo2b, bo2, o1t,
                                            (float*)d_out + (size_t)t * OUTF);
  }
  aux_reduce<<<dim3(1), blk, 0, stream>>>(auxp, TT * gateGrid, aux,
                                          1.f / ((float)BB * (float)HH));
}